// Round 12
// baseline (383.319 us; speedup 1.0000x reference)
//
#include <hip/hip_runtime.h>
#include <math.h>

#define N0 200000
#define N1 50000
#define N2 10000
#define E0 750000
#define E1 150000
#define D 256
#define OUT 64
#define CAP 64

#define BM 64
#define BN 128
#define FS_ROWS 32

typedef unsigned int uint32;
using short8 = __attribute__((ext_vector_type(8))) short;
using f32x4 = __attribute__((ext_vector_type(4))) float;

// ---- bf16 split helpers: v ~ bf16(hi) + bf16(lo) ----
__device__ __forceinline__ unsigned short bf16_rne(float f) {
    unsigned int u = __float_as_uint(f);
    unsigned int r = (u + 0x7FFFu + ((u >> 16) & 1u)) >> 16;
    return (unsigned short)r;
}
__device__ __forceinline__ float bf16_f32(unsigned short h) {
    return __uint_as_float(((unsigned int)h) << 16);
}

// direct global->LDS copy, 16B per lane. LDS dest = wave-uniform base + lane*16.
__device__ __forceinline__ void gload_lds16(const void* g, void* l) {
    __builtin_amdgcn_global_load_lds(
        (const __attribute__((address_space(1))) unsigned int*)g,
        (__attribute__((address_space(3))) unsigned int*)l, 16, 0, 0);
}

// ---------------------------------------------------------------------------
// Build per-target edge lists (capacity CAP per target; max degree ~38).
// ---------------------------------------------------------------------------
__global__ void fill_edges(const int* __restrict__ src, const int* __restrict__ dst,
                           int* __restrict__ cnt, int* __restrict__ eidx, int E) {
    int e = blockIdx.x * blockDim.x + threadIdx.x;
    if (e >= E) return;
    int d = dst[e];
    int pos = atomicAdd(&cnt[d], 1);
    if (pos < CAP) eidx[d * CAP + pos] = src[e];
}

// ---------------------------------------------------------------------------
// Split fp32 -> (hi bf16, lo bf16) planes. 4 elems/thread.
// ---------------------------------------------------------------------------
__global__ void split_f32(const float* __restrict__ in, unsigned short* __restrict__ hi,
                          unsigned short* __restrict__ lo, int n4) {
    int i = blockIdx.x * blockDim.x + threadIdx.x;
    if (i >= n4) return;
    float4 v = *reinterpret_cast<const float4*>(in + (size_t)i * 4);
    ushort4 h, l;
    h.x = bf16_rne(v.x); l.x = bf16_rne(v.x - bf16_f32(h.x));
    h.y = bf16_rne(v.y); l.y = bf16_rne(v.y - bf16_f32(h.y));
    h.z = bf16_rne(v.z); l.z = bf16_rne(v.z - bf16_f32(h.z));
    h.w = bf16_rne(v.w); l.w = bf16_rne(v.w - bf16_f32(h.w));
    *reinterpret_cast<ushort4*>(hi + (size_t)i * 4) = h;
    *reinterpret_cast<ushort4*>(lo + (size_t)i * 4) = l;
}

// ---------------------------------------------------------------------------
// Pack W transposed+split: WThi/WTlo[n][kc] (kc<256 -> Wl[kc][n], else Wr).
// ---------------------------------------------------------------------------
__global__ void pack_wt(const float* __restrict__ Wl, const float* __restrict__ Wr,
                        unsigned short* __restrict__ WThi, unsigned short* __restrict__ WTlo) {
    int n = blockIdx.x;
    int kc = threadIdx.x;
    float v = (kc < 256) ? Wl[(size_t)kc * D + n] : Wr[(size_t)(kc - 256) * D + n];
    unsigned short h = bf16_rne(v);
    WThi[(size_t)n * 512 + kc] = h;
    WTlo[(size_t)n * 512 + kc] = bf16_rne(v - bf16_f32(h));
}

// ---------------------------------------------------------------------------
// Mean-aggregate neighbor rows -> split hi/lo bf16 planes.
// At the per-CU delivery ceiling (24.4 GB/s/CU = m13 streaming limit) — done.
// ---------------------------------------------------------------------------
template<int SRCMODE>
__global__ void aggregate_s(const void* __restrict__ srcA, const void* __restrict__ srcB,
                            const int* __restrict__ cnt, const int* __restrict__ eidx,
                            unsigned short* __restrict__ aggHi, unsigned short* __restrict__ aggLo,
                            int T) {
    int wave = threadIdx.x >> 6;
    int lane = threadIdx.x & 63;
    int t = blockIdx.x * 4 + wave;
    if (t >= T) return;
    int deg = cnt[t];
    int n = deg < CAP ? deg : CAP;
    int vidx = eidx[(size_t)t * CAP + lane];
    float a0 = 0.f, a1 = 0.f, a2 = 0.f, a3 = 0.f;

    for (int j0 = 0; j0 < n; j0 += 4) {
        int   s[4];
        float w[4];
        #pragma unroll
        for (int jj = 0; jj < 4; ++jj) {
            int j = j0 + jj;
            int sv = __shfl(vidx, j);
            bool act = j < n;
            s[jj] = act ? sv : 0;
            w[jj] = act ? 1.f : 0.f;
        }
        if constexpr (SRCMODE == 0) {
            const float* sp = (const float*)srcA;
            float4 v[4];
            #pragma unroll
            for (int jj = 0; jj < 4; ++jj)
                v[jj] = *reinterpret_cast<const float4*>(sp + (size_t)s[jj] * D + lane * 4);
            #pragma unroll
            for (int jj = 0; jj < 4; ++jj) {
                a0 += w[jj] * v[jj].x; a1 += w[jj] * v[jj].y;
                a2 += w[jj] * v[jj].z; a3 += w[jj] * v[jj].w;
            }
        } else {
            const unsigned short* sh = (const unsigned short*)srcA;
            const unsigned short* sl = (const unsigned short*)srcB;
            ushort4 uh[4], ul[4];
            #pragma unroll
            for (int jj = 0; jj < 4; ++jj) {
                uh[jj] = *reinterpret_cast<const ushort4*>(sh + (size_t)s[jj] * D + lane * 4);
                ul[jj] = *reinterpret_cast<const ushort4*>(sl + (size_t)s[jj] * D + lane * 4);
            }
            #pragma unroll
            for (int jj = 0; jj < 4; ++jj) {
                a0 += w[jj] * (bf16_f32(uh[jj].x) + bf16_f32(ul[jj].x));
                a1 += w[jj] * (bf16_f32(uh[jj].y) + bf16_f32(ul[jj].y));
                a2 += w[jj] * (bf16_f32(uh[jj].z) + bf16_f32(ul[jj].z));
                a3 += w[jj] * (bf16_f32(uh[jj].w) + bf16_f32(ul[jj].w));
            }
        }
    }

    float sc = deg > 0 ? 1.0f / (float)deg : 0.0f;
    a0 *= sc; a1 *= sc; a2 *= sc; a3 *= sc;
    ushort4 oh, ol;
    oh.x = bf16_rne(a0); ol.x = bf16_rne(a0 - bf16_f32(oh.x));
    oh.y = bf16_rne(a1); ol.y = bf16_rne(a1 - bf16_f32(oh.y));
    oh.z = bf16_rne(a2); ol.z = bf16_rne(a2 - bf16_f32(oh.z));
    oh.w = bf16_rne(a3); ol.w = bf16_rne(a3 - bf16_f32(oh.w));
    *reinterpret_cast<ushort4*>(aggHi + (size_t)t * D + lane * 4) = oh;
    *reinterpret_cast<ushort4*>(aggLo + (size_t)t * D + lane * 4) = ol;
}

// ---------------------------------------------------------------------------
// Split-bf16 MFMA GEMM, 64x128 tile.
// Round-12 change: B (WT, 0.5 MB, L2-resident) is NOT staged in LDS.
// B fragments load straight from global into registers (contiguous 8 bf16
// along k, 16B/lane) — removes half the barrier-drained staging, kills B's
// LDS round-trip, and lets B loads pipeline under MFMA via vmcnt scheduling.
// Round-11 budget analysis: gemm0 ~140 us = 274 TF effective, 2-barrier
// stall-bound (48 KB staged + vmcnt(0) drain per k-step). LDS now 16 KB.
// A-side keeps verified gload_lds w16 + pre-swizzled source + XOR reads.
// ---------------------------------------------------------------------------
template<int ACT>
__global__ void __launch_bounds__(256, 3)
gemm_split(const unsigned short* __restrict__ A1hi, const unsigned short* __restrict__ A1lo,
           const unsigned short* __restrict__ A2hi, const unsigned short* __restrict__ A2lo,
           const unsigned short* __restrict__ WThi, const unsigned short* __restrict__ WTlo,
           const float* __restrict__ bias, unsigned short* __restrict__ Chi,
           unsigned short* __restrict__ Clo, float* __restrict__ Cf, int M) {
    __shared__ __align__(16) char sAhi[BM * 128];   //  8 KB
    __shared__ __align__(16) char sAlo[BM * 128];   //  8 KB

    const int tid = threadIdx.x;
    const int m0 = blockIdx.x * BM;
    const int n0 = blockIdx.y * BN;
    const int wid = tid >> 6, lane = tid & 63;
    const int lr = lane & 15;
    const int hi2 = lane >> 4;

    const int srow = lane >> 3;                    // row within 8-row chunk
    const int scol = ((lane & 7) ^ srow) << 4;     // pre-swizzled source byte col

    // B fragment rows (global WT rows), fixed per thread
    const unsigned short* Bh0 = WThi + (size_t)(n0 + wid * 32 + 0 * 16 + lr) * 512;
    const unsigned short* Bh1 = WThi + (size_t)(n0 + wid * 32 + 1 * 16 + lr) * 512;
    const unsigned short* Bl0 = WTlo + (size_t)(n0 + wid * 32 + 0 * 16 + lr) * 512;
    const unsigned short* Bl1 = WTlo + (size_t)(n0 + wid * 32 + 1 * 16 + lr) * 512;

    f32x4 acc[4][2];
    #pragma unroll
    for (int i = 0; i < 4; ++i)
        #pragma unroll
        for (int j = 0; j < 2; ++j)
            acc[i][j] = (f32x4){0.f, 0.f, 0.f, 0.f};

    for (int k0 = 0; k0 < 512; k0 += 64) {
        if (k0) __syncthreads();   // prior compute done before LDS overwrite
        const char* Ah = (const char*)((k0 < 256) ? A1hi : A2hi);
        const char* Al = (const char*)((k0 < 256) ? A1lo : A2lo);
        const int kc = k0 & 255;
        // A: 8 chunks of 8 rows, 2 per wave
        #pragma unroll
        for (int i = 0; i < 2; ++i) {
            int ch = wid * 2 + i;
            int row = ch * 8 + srow;
            size_t ga = ((size_t)(m0 + row) * D + kc) * 2 + scol;
            gload_lds16(Ah + ga, sAhi + ch * 1024);
            gload_lds16(Al + ga, sAlo + ch * 1024);
        }
        __syncthreads();   // vmcnt(0) drained by compiler before barrier

        #pragma unroll
        for (int slab = 0; slab < 2; ++slab) {
            const int z = slab * 64 + hi2 * 16;        // byte offset in LDS row
            const int ze = k0 + slab * 32 + hi2 * 8;   // elem offset in WT row
            short8 ah[4], al[4], bh[2], bl[2];
            #pragma unroll
            for (int f = 0; f < 4; ++f) {
                int ra = f * 16 + lr;
                int oa = ra * 128 + (z ^ ((ra & 7) << 4));
                ah[f] = *reinterpret_cast<const short8*>(sAhi + oa);
                al[f] = *reinterpret_cast<const short8*>(sAlo + oa);
            }
            bh[0] = *reinterpret_cast<const short8*>(Bh0 + ze);
            bh[1] = *reinterpret_cast<const short8*>(Bh1 + ze);
            bl[0] = *reinterpret_cast<const short8*>(Bl0 + ze);
            bl[1] = *reinterpret_cast<const short8*>(Bl1 + ze);
            #pragma unroll
            for (int i = 0; i < 4; ++i)
                #pragma unroll
                for (int j = 0; j < 2; ++j) {
                    acc[i][j] = __builtin_amdgcn_mfma_f32_16x16x32_bf16(ah[i], bh[j], acc[i][j], 0, 0, 0);
                    acc[i][j] = __builtin_amdgcn_mfma_f32_16x16x32_bf16(ah[i], bl[j], acc[i][j], 0, 0, 0);
                    acc[i][j] = __builtin_amdgcn_mfma_f32_16x16x32_bf16(al[i], bh[j], acc[i][j], 0, 0, 0);
                }
        }
    }

    // epilogue: D[row][col], col = lane&15, row = (lane>>4)*4 + reg
    #pragma unroll
    for (int fn = 0; fn < 2; ++fn) {
        int col = n0 + wid * 32 + fn * 16 + lr;
        float bv = bias[col];
        #pragma unroll
        for (int fm = 0; fm < 4; ++fm) {
            int rbase = m0 + fm * 16 + hi2 * 4;
            #pragma unroll
            for (int r = 0; r < 4; ++r) {
                int m = rbase + r;
                if (m < M) {
                    float v = acc[fm][fn][r] + bv;
                    if (ACT == 0) {
                        v = fmaxf(v, 0.f);
                        unsigned short h = bf16_rne(v);
                        Chi[(size_t)m * D + col] = h;
                        Clo[(size_t)m * D + col] = bf16_rne(v - bf16_f32(h));
                    } else {
                        Cf[(size_t)m * D + col] = tanhf(v);
                    }
                }
            }
        }
    }
}

// ---------------------------------------------------------------------------
// Final: out[M][64] = softmax(H @ Wlin + blin).
// Wlin in LDS once/block; H via wave-uniform scalar loads; 4 independent
// partial accumulators (chain = fma latency only).
// ---------------------------------------------------------------------------
__global__ void __launch_bounds__(256)
final_softmax(const float* __restrict__ H, const float* __restrict__ Wlin,
              const float* __restrict__ blin, float* __restrict__ out, int M) {
    __shared__ __align__(16) float sW[D * OUT];   // 64 KB
    const int tid = threadIdx.x;
    #pragma unroll
    for (int i = 0; i < 16; ++i) {
        int idx = (i * 256 + tid) * 4;
        *reinterpret_cast<float4*>(&sW[idx]) = *reinterpret_cast<const float4*>(&Wlin[idx]);
    }
    __syncthreads();

    const int wave = tid >> 6, lane = tid & 63;
    const float bl = blin[lane];
    int r0 = blockIdx.x * FS_ROWS + wave * (FS_ROWS / 4);
    int r1 = r0 + FS_ROWS / 4;
    for (int r = r0; r < r1 && r < M; ++r) {
        const float* hrow = H + (size_t)r * D;   // wave-uniform -> scalar loads
        float a0 = 0.f, a1 = 0.f, a2 = 0.f, a3 = 0.f;
        #pragma unroll 8
        for (int k = 0; k < D; k += 4) {
            a0 += hrow[k + 0] * sW[(k + 0) * OUT + lane];
            a1 += hrow[k + 1] * sW[(k + 1) * OUT + lane];
            a2 += hrow[k + 2] * sW[(k + 2) * OUT + lane];
            a3 += hrow[k + 3] * sW[(k + 3) * OUT + lane];
        }
        float acc = (a0 + a1) + (a2 + a3) + bl;
        float mx = acc;
        #pragma unroll
        for (int off = 32; off > 0; off >>= 1) mx = fmaxf(mx, __shfl_xor(mx, off));
        float e = __expf(acc - mx);
        float s = e;
        #pragma unroll
        for (int off = 32; off > 0; off >>= 1) s += __shfl_xor(s, off);
        out[(size_t)r * OUT + lane] = e / s;
    }
}

extern "C" void kernel_launch(void* const* d_in, const int* in_sizes, int n_in,
                              void* d_out, int out_size, void* d_ws, size_t ws_size,
                              hipStream_t stream) {
    const float* x    = (const float*)d_in[0];
    const int*   src0 = (const int*)d_in[1];
    const int*   dst0 = (const int*)d_in[2];
    const int*   src1 = (const int*)d_in[3];
    const int*   dst1 = (const int*)d_in[4];
    const float* Wl0  = (const float*)d_in[5];
    const float* bl0  = (const float*)d_in[6];
    const float* Wr0  = (const float*)d_in[7];
    const float* Wl1  = (const float*)d_in[8];
    const float* bl1  = (const float*)d_in[9];
    const float* Wr1  = (const float*)d_in[10];
    const float* Wlin = (const float*)d_in[11];
    const float* blin = (const float*)d_in[12];

    const int PAD1 = 50048;   // 782*64 (gload_lds reads unmasked -> pad rows)
    const int PAD2 = 10112;   // 158*64

    char* ws = (char*)d_ws;
    size_t off = 0;
    auto alloc = [&](size_t bytes) {
        void* p = ws + off;
        off += (bytes + 255) & ~(size_t)255;
        return p;
    };
    int* cnt0  = (int*)alloc((size_t)N1 * 4);
    int* eidx0 = (int*)alloc((size_t)N1 * CAP * 4);
    int* cnt1  = (int*)alloc((size_t)N2 * 4);
    int* eidx1 = (int*)alloc((size_t)N2 * CAP * 4);
    unsigned short* agg0hi = (unsigned short*)alloc((size_t)PAD1 * D * 2);
    unsigned short* agg0lo = (unsigned short*)alloc((size_t)PAD1 * D * 2);
    unsigned short* xhi    = (unsigned short*)alloc((size_t)PAD1 * D * 2);
    unsigned short* xlo    = (unsigned short*)alloc((size_t)PAD1 * D * 2);
    unsigned short* h0hi   = (unsigned short*)alloc((size_t)N1 * D * 2);
    unsigned short* h0lo   = (unsigned short*)alloc((size_t)N1 * D * 2);
    unsigned short* agg1hi = (unsigned short*)alloc((size_t)PAD2 * D * 2);
    unsigned short* agg1lo = (unsigned short*)alloc((size_t)PAD2 * D * 2);
    float* h1f = (float*)alloc((size_t)N2 * D * 4);
    unsigned short* WThi0 = (unsigned short*)alloc((size_t)D * 512 * 2);
    unsigned short* WTlo0 = (unsigned short*)alloc((size_t)D * 512 * 2);
    unsigned short* WThi1 = (unsigned short*)alloc((size_t)D * 512 * 2);
    unsigned short* WTlo1 = (unsigned short*)alloc((size_t)D * 512 * 2);

    hipMemsetAsync(cnt0, 0, (size_t)N1 * 4, stream);
    hipMemsetAsync(cnt1, 0, (size_t)N2 * 4, stream);

    split_f32<<<(N1 * D / 4 + 255) / 256, 256, 0, stream>>>(x, xhi, xlo, N1 * D / 4);
    pack_wt<<<256, 512, 0, stream>>>(Wl0, Wr0, WThi0, WTlo0);
    pack_wt<<<256, 512, 0, stream>>>(Wl1, Wr1, WThi1, WTlo1);

    fill_edges<<<(E0 + 255) / 256, 256, 0, stream>>>(src0, dst0, cnt0, eidx0, E0);
    aggregate_s<0><<<(N1 + 3) / 4, 256, 0, stream>>>(x, nullptr, cnt0, eidx0, agg0hi, agg0lo, N1);
    gemm_split<0><<<dim3((N1 + BM - 1) / BM, 2), 256, 0, stream>>>(
        agg0hi, agg0lo, xhi, xlo, WThi0, WTlo0, bl0, h0hi, h0lo, (float*)nullptr, N1);

    fill_edges<<<(E1 + 255) / 256, 256, 0, stream>>>(src1, dst1, cnt1, eidx1, E1);
    aggregate_s<1><<<(N2 + 3) / 4, 256, 0, stream>>>(h0hi, h0lo, cnt1, eidx1, agg1hi, agg1lo, N2);
    gemm_split<1><<<dim3((N2 + BM - 1) / BM, 2), 256, 0, stream>>>(
        agg1hi, agg1lo, h0hi, h0lo, WThi1, WTlo1, bl1,
        (unsigned short*)nullptr, (unsigned short*)nullptr, h1f, N2);

    final_softmax<<<(N2 + FS_ROWS - 1) / FS_ROWS, 256, 0, stream>>>(
        h1f, Wlin, blin, (float*)d_out, N2);
}

// Round 15
// 372.728 us; speedup vs baseline: 1.0284x; 1.0284x over previous
//
#include <hip/hip_runtime.h>
#include <math.h>

#define N0 200000
#define N1 50000
#define N2 10000
#define E0 750000
#define E1 150000
#define D 256
#define OUT 64
#define CAP 64

#define BM 64
#define BN 128
#define FS_ROWS 32

typedef unsigned int uint32;
using short8 = __attribute__((ext_vector_type(8))) short;
using f32x4 = __attribute__((ext_vector_type(4))) float;

// ---- bf16 split helpers: v ~ bf16(hi) + bf16(lo) ----
__device__ __forceinline__ unsigned short bf16_rne(float f) {
    unsigned int u = __float_as_uint(f);
    unsigned int r = (u + 0x7FFFu + ((u >> 16) & 1u)) >> 16;
    return (unsigned short)r;
}
__device__ __forceinline__ float bf16_f32(unsigned short h) {
    return __uint_as_float(((unsigned int)h) << 16);
}

// direct global->LDS copy, 16B per lane. LDS dest = wave-uniform base + lane*16.
__device__ __forceinline__ void gload_lds16(const void* g, void* l) {
    __builtin_amdgcn_global_load_lds(
        (const __attribute__((address_space(1))) unsigned int*)g,
        (__attribute__((address_space(3))) unsigned int*)l, 16, 0, 0);
}

// ---------------------------------------------------------------------------
// Build per-target edge lists (capacity CAP per target; max degree ~38).
// ---------------------------------------------------------------------------
__global__ void fill_edges(const int* __restrict__ src, const int* __restrict__ dst,
                           int* __restrict__ cnt, int* __restrict__ eidx, int E) {
    int e = blockIdx.x * blockDim.x + threadIdx.x;
    if (e >= E) return;
    int d = dst[e];
    int pos = atomicAdd(&cnt[d], 1);
    if (pos < CAP) eidx[d * CAP + pos] = src[e];
}

// ---------------------------------------------------------------------------
// Split fp32 -> (hi bf16, lo bf16) planes. 4 elems/thread.
// ---------------------------------------------------------------------------
__global__ void split_f32(const float* __restrict__ in, unsigned short* __restrict__ hi,
                          unsigned short* __restrict__ lo, int n4) {
    int i = blockIdx.x * blockDim.x + threadIdx.x;
    if (i >= n4) return;
    float4 v = *reinterpret_cast<const float4*>(in + (size_t)i * 4);
    ushort4 h, l;
    h.x = bf16_rne(v.x); l.x = bf16_rne(v.x - bf16_f32(h.x));
    h.y = bf16_rne(v.y); l.y = bf16_rne(v.y - bf16_f32(h.y));
    h.z = bf16_rne(v.z); l.z = bf16_rne(v.z - bf16_f32(h.z));
    h.w = bf16_rne(v.w); l.w = bf16_rne(v.w - bf16_f32(h.w));
    *reinterpret_cast<ushort4*>(hi + (size_t)i * 4) = h;
    *reinterpret_cast<ushort4*>(lo + (size_t)i * 4) = l;
}

// ---------------------------------------------------------------------------
// Pack W transposed+split: WThi/WTlo[n][kc] (kc<256 -> Wl[kc][n], else Wr).
// ---------------------------------------------------------------------------
__global__ void pack_wt(const float* __restrict__ Wl, const float* __restrict__ Wr,
                        unsigned short* __restrict__ WThi, unsigned short* __restrict__ WTlo) {
    int n = blockIdx.x;
    int kc = threadIdx.x;
    float v = (kc < 256) ? Wl[(size_t)kc * D + n] : Wr[(size_t)(kc - 256) * D + n];
    unsigned short h = bf16_rne(v);
    WThi[(size_t)n * 512 + kc] = h;
    WTlo[(size_t)n * 512 + kc] = bf16_rne(v - bf16_f32(h));
}

// ---------------------------------------------------------------------------
// Mean-aggregate neighbor rows -> split hi/lo bf16 planes.
// At the per-CU delivery ceiling (24.4 GB/s/CU = m13 streaming limit) — done.
// ---------------------------------------------------------------------------
template<int SRCMODE>
__global__ void aggregate_s(const void* __restrict__ srcA, const void* __restrict__ srcB,
                            const int* __restrict__ cnt, const int* __restrict__ eidx,
                            unsigned short* __restrict__ aggHi, unsigned short* __restrict__ aggLo,
                            int T) {
    int wave = threadIdx.x >> 6;
    int lane = threadIdx.x & 63;
    int t = blockIdx.x * 4 + wave;
    if (t >= T) return;
    int deg = cnt[t];
    int n = deg < CAP ? deg : CAP;
    int vidx = eidx[(size_t)t * CAP + lane];
    float a0 = 0.f, a1 = 0.f, a2 = 0.f, a3 = 0.f;

    for (int j0 = 0; j0 < n; j0 += 4) {
        int   s[4];
        float w[4];
        #pragma unroll
        for (int jj = 0; jj < 4; ++jj) {
            int j = j0 + jj;
            int sv = __shfl(vidx, j);
            bool act = j < n;
            s[jj] = act ? sv : 0;
            w[jj] = act ? 1.f : 0.f;
        }
        if constexpr (SRCMODE == 0) {
            const float* sp = (const float*)srcA;
            float4 v[4];
            #pragma unroll
            for (int jj = 0; jj < 4; ++jj)
                v[jj] = *reinterpret_cast<const float4*>(sp + (size_t)s[jj] * D + lane * 4);
            #pragma unroll
            for (int jj = 0; jj < 4; ++jj) {
                a0 += w[jj] * v[jj].x; a1 += w[jj] * v[jj].y;
                a2 += w[jj] * v[jj].z; a3 += w[jj] * v[jj].w;
            }
        } else {
            const unsigned short* sh = (const unsigned short*)srcA;
            const unsigned short* sl = (const unsigned short*)srcB;
            ushort4 uh[4], ul[4];
            #pragma unroll
            for (int jj = 0; jj < 4; ++jj) {
                uh[jj] = *reinterpret_cast<const ushort4*>(sh + (size_t)s[jj] * D + lane * 4);
                ul[jj] = *reinterpret_cast<const ushort4*>(sl + (size_t)s[jj] * D + lane * 4);
            }
            #pragma unroll
            for (int jj = 0; jj < 4; ++jj) {
                a0 += w[jj] * (bf16_f32(uh[jj].x) + bf16_f32(ul[jj].x));
                a1 += w[jj] * (bf16_f32(uh[jj].y) + bf16_f32(ul[jj].y));
                a2 += w[jj] * (bf16_f32(uh[jj].z) + bf16_f32(ul[jj].z));
                a3 += w[jj] * (bf16_f32(uh[jj].w) + bf16_f32(ul[jj].w));
            }
        }
    }

    float sc = deg > 0 ? 1.0f / (float)deg : 0.0f;
    a0 *= sc; a1 *= sc; a2 *= sc; a3 *= sc;
    ushort4 oh, ol;
    oh.x = bf16_rne(a0); ol.x = bf16_rne(a0 - bf16_f32(oh.x));
    oh.y = bf16_rne(a1); ol.y = bf16_rne(a1 - bf16_f32(oh.y));
    oh.z = bf16_rne(a2); ol.z = bf16_rne(a2 - bf16_f32(oh.z));
    oh.w = bf16_rne(a3); ol.w = bf16_rne(a3 - bf16_f32(oh.w));
    *reinterpret_cast<ushort4*>(aggHi + (size_t)t * D + lane * 4) = oh;
    *reinterpret_cast<ushort4*>(aggLo + (size_t)t * D + lane * 4) = ol;
}

// ---------------------------------------------------------------------------
// Split-bf16 MFMA GEMM, 64x128 tile, BK=32, DOUBLE-BUFFERED 2-phase schedule.
// Round-12 post-mortem: B-from-global regressed (L2 latency on the MFMA
// critical path) -> B back in LDS. Round-13 change: catalog minimum-2-phase —
// issue next tile's global_load_lds BEFORE current tile's ds_read+MFMA, one
// vmcnt(0)+barrier per tile, ping-pong LDS buffers. hi/lo planes interleaved
// in one 128B LDS row (bytes 0-63 hi, 64-127 lo) so the verified XOR
// involution (slot ^= (row&7)<<4) applies on both source and read (rule #21);
// conflicts stay at free 2-way. LDS 2*(8+16) = 48 KB -> 3 blocks/CU.
// ---------------------------------------------------------------------------
template<int ACT>
__global__ void __launch_bounds__(256, 3)
gemm_split(const unsigned short* __restrict__ A1hi, const unsigned short* __restrict__ A1lo,
           const unsigned short* __restrict__ A2hi, const unsigned short* __restrict__ A2lo,
           const unsigned short* __restrict__ WThi, const unsigned short* __restrict__ WTlo,
           const float* __restrict__ bias, unsigned short* __restrict__ Chi,
           unsigned short* __restrict__ Clo, float* __restrict__ Cf, int M) {
    __shared__ __align__(16) char sA[2][BM * 128];   // 2 x 8 KB  (hi|lo interleaved)
    __shared__ __align__(16) char sB[2][BN * 128];   // 2 x 16 KB

    const int tid = threadIdx.x;
    const int m0 = blockIdx.x * BM;
    const int n0 = blockIdx.y * BN;
    const int wid = tid >> 6, lane = tid & 63;
    const int lr = lane & 15;
    const int hi2 = lane >> 4;

    // staging lane decomposition: chunk = 8 rows x 128B (1 KB per gload-wave)
    const int srow = lane >> 3;                      // row within chunk
    const int sel  = (lane & 7) ^ srow;              // swizzled 16B slot 0..7
    const int spl  = sel >> 2;                       // 0 = hi plane, 1 = lo
    const int scol = (sel & 3) << 4;                 // byte col within plane (64B)

    f32x4 acc[4][2];
    #pragma unroll
    for (int i = 0; i < 4; ++i)
        #pragma unroll
        for (int j = 0; j < 2; ++j)
            acc[i][j] = (f32x4){0.f, 0.f, 0.f, 0.f};

    auto STAGE = [&](int buf, int t) {
        const int k0 = t * 32;
        const char* Ah = (const char*)((k0 < 256) ? A1hi : A2hi);
        const char* Al = (const char*)((k0 < 256) ? A1lo : A2lo);
        const char* Asrc = spl ? Al : Ah;
        const char* Bsrc = spl ? (const char*)WTlo : (const char*)WThi;
        const int kc = k0 & 255;
        #pragma unroll
        for (int i = 0; i < 2; ++i) {              // A: 8 chunks, 2 per wave
            int ch = wid * 2 + i;
            int row = m0 + ch * 8 + srow;
            gload_lds16(Asrc + ((size_t)row * D + kc) * 2 + scol, sA[buf] + ch * 1024);
        }
        #pragma unroll
        for (int i = 0; i < 4; ++i) {              // B: 16 chunks, 4 per wave
            int ch = wid * 4 + i;
            int row = n0 + ch * 8 + srow;
            gload_lds16(Bsrc + ((size_t)row * 512 + k0) * 2 + scol, sB[buf] + ch * 1024);
        }
    };

    auto COMPUTE = [&](int buf) {
        short8 ah[4], al[4], bh[2], bl[2];
        #pragma unroll
        for (int f = 0; f < 4; ++f) {
            int ra = f * 16 + lr;
            int swz = (ra & 7) << 4;
            ah[f] = *reinterpret_cast<const short8*>(sA[buf] + ra * 128 + ((hi2 * 16) ^ swz));
            al[f] = *reinterpret_cast<const short8*>(sA[buf] + ra * 128 + ((64 + hi2 * 16) ^ swz));
        }
        #pragma unroll
        for (int g = 0; g < 2; ++g) {
            int rb = wid * 32 + g * 16 + lr;
            int swz = (rb & 7) << 4;
            bh[g] = *reinterpret_cast<const short8*>(sB[buf] + rb * 128 + ((hi2 * 16) ^ swz));
            bl[g] = *reinterpret_cast<const short8*>(sB[buf] + rb * 128 + ((64 + hi2 * 16) ^ swz));
        }
        #pragma unroll
        for (int i = 0; i < 4; ++i)
            #pragma unroll
            for (int j = 0; j < 2; ++j) {
                acc[i][j] = __builtin_amdgcn_mfma_f32_16x16x32_bf16(ah[i], bh[j], acc[i][j], 0, 0, 0);
                acc[i][j] = __builtin_amdgcn_mfma_f32_16x16x32_bf16(ah[i], bl[j], acc[i][j], 0, 0, 0);
                acc[i][j] = __builtin_amdgcn_mfma_f32_16x16x32_bf16(al[i], bh[j], acc[i][j], 0, 0, 0);
            }
    };

    // prologue: tile 0 into buf 0
    STAGE(0, 0);
    __syncthreads();                 // vmcnt(0) drain + barrier
    // 2-phase main loop: stage(next) BEFORE compute(current); 1 barrier/tile
    #pragma unroll
    for (int tt = 0; tt < 8; ++tt) {
        STAGE(1, 2 * tt + 1);        // in flight during COMPUTE(0)
        COMPUTE(0);
        __syncthreads();
        if (tt < 7) STAGE(0, 2 * tt + 2);
        COMPUTE(1);
        __syncthreads();
    }

    // epilogue: D[row][col], col = lane&15, row = (lane>>4)*4 + reg
    #pragma unroll
    for (int fn = 0; fn < 2; ++fn) {
        int col = n0 + wid * 32 + fn * 16 + lr;
        float bv = bias[col];
        #pragma unroll
        for (int fm = 0; fm < 4; ++fm) {
            int rbase = m0 + fm * 16 + hi2 * 4;
            #pragma unroll
            for (int r = 0; r < 4; ++r) {
                int m = rbase + r;
                if (m < M) {
                    float v = acc[fm][fn][r] + bv;
                    if (ACT == 0) {
                        v = fmaxf(v, 0.f);
                        unsigned short h = bf16_rne(v);
                        Chi[(size_t)m * D + col] = h;
                        Clo[(size_t)m * D + col] = bf16_rne(v - bf16_f32(h));
                    } else {
                        Cf[(size_t)m * D + col] = tanhf(v);
                    }
                }
            }
        }
    }
}

// ---------------------------------------------------------------------------
// Final: out[M][64] = softmax(H @ Wlin + blin).
// Wlin in LDS once/block; H via wave-uniform scalar loads; 4 independent
// partial accumulators (chain = fma latency only).
// ---------------------------------------------------------------------------
__global__ void __launch_bounds__(256)
final_softmax(const float* __restrict__ H, const float* __restrict__ Wlin,
              const float* __restrict__ blin, float* __restrict__ out, int M) {
    __shared__ __align__(16) float sW[D * OUT];   // 64 KB
    const int tid = threadIdx.x;
    #pragma unroll
    for (int i = 0; i < 16; ++i) {
        int idx = (i * 256 + tid) * 4;
        *reinterpret_cast<float4*>(&sW[idx]) = *reinterpret_cast<const float4*>(&Wlin[idx]);
    }
    __syncthreads();

    const int wave = tid >> 6, lane = tid & 63;
    const float bl = blin[lane];
    int r0 = blockIdx.x * FS_ROWS + wave * (FS_ROWS / 4);
    int r1 = r0 + FS_ROWS / 4;
    for (int r = r0; r < r1 && r < M; ++r) {
        const float* hrow = H + (size_t)r * D;   // wave-uniform -> scalar loads
        float a0 = 0.f, a1 = 0.f, a2 = 0.f, a3 = 0.f;
        #pragma unroll 8
        for (int k = 0; k < D; k += 4) {
            a0 += hrow[k + 0] * sW[(k + 0) * OUT + lane];
            a1 += hrow[k + 1] * sW[(k + 1) * OUT + lane];
            a2 += hrow[k + 2] * sW[(k + 2) * OUT + lane];
            a3 += hrow[k + 3] * sW[(k + 3) * OUT + lane];
        }
        float acc = (a0 + a1) + (a2 + a3) + bl;
        float mx = acc;
        #pragma unroll
        for (int off = 32; off > 0; off >>= 1) mx = fmaxf(mx, __shfl_xor(mx, off));
        float e = __expf(acc - mx);
        float s = e;
        #pragma unroll
        for (int off = 32; off > 0; off >>= 1) s += __shfl_xor(s, off);
        out[(size_t)r * OUT + lane] = e / s;
    }
}

extern "C" void kernel_launch(void* const* d_in, const int* in_sizes, int n_in,
                              void* d_out, int out_size, void* d_ws, size_t ws_size,
                              hipStream_t stream) {
    const float* x    = (const float*)d_in[0];
    const int*   src0 = (const int*)d_in[1];
    const int*   dst0 = (const int*)d_in[2];
    const int*   src1 = (const int*)d_in[3];
    const int*   dst1 = (const int*)d_in[4];
    const float* Wl0  = (const float*)d_in[5];
    const float* bl0  = (const float*)d_in[6];
    const float* Wr0  = (const float*)d_in[7];
    const float* Wl1  = (const float*)d_in[8];
    const float* bl1  = (const float*)d_in[9];
    const float* Wr1  = (const float*)d_in[10];
    const float* Wlin = (const float*)d_in[11];
    const float* blin = (const float*)d_in[12];

    const int PAD1 = 50048;   // 782*64 (gload_lds reads unmasked -> pad rows)
    const int PAD2 = 10112;   // 158*64

    char* ws = (char*)d_ws;
    size_t off = 0;
    auto alloc = [&](size_t bytes) {
        void* p = ws + off;
        off += (bytes + 255) & ~(size_t)255;
        return p;
    };
    int* cnt0  = (int*)alloc((size_t)N1 * 4);
    int* eidx0 = (int*)alloc((size_t)N1 * CAP * 4);
    int* cnt1  = (int*)alloc((size_t)N2 * 4);
    int* eidx1 = (int*)alloc((size_t)N2 * CAP * 4);
    unsigned short* agg0hi = (unsigned short*)alloc((size_t)PAD1 * D * 2);
    unsigned short* agg0lo = (unsigned short*)alloc((size_t)PAD1 * D * 2);
    unsigned short* xhi    = (unsigned short*)alloc((size_t)PAD1 * D * 2);
    unsigned short* xlo    = (unsigned short*)alloc((size_t)PAD1 * D * 2);
    unsigned short* h0hi   = (unsigned short*)alloc((size_t)N1 * D * 2);
    unsigned short* h0lo   = (unsigned short*)alloc((size_t)N1 * D * 2);
    unsigned short* agg1hi = (unsigned short*)alloc((size_t)PAD2 * D * 2);
    unsigned short* agg1lo = (unsigned short*)alloc((size_t)PAD2 * D * 2);
    float* h1f = (float*)alloc((size_t)N2 * D * 4);
    unsigned short* WThi0 = (unsigned short*)alloc((size_t)D * 512 * 2);
    unsigned short* WTlo0 = (unsigned short*)alloc((size_t)D * 512 * 2);
    unsigned short* WThi1 = (unsigned short*)alloc((size_t)D * 512 * 2);
    unsigned short* WTlo1 = (unsigned short*)alloc((size_t)D * 512 * 2);

    hipMemsetAsync(cnt0, 0, (size_t)N1 * 4, stream);
    hipMemsetAsync(cnt1, 0, (size_t)N2 * 4, stream);

    split_f32<<<(N1 * D / 4 + 255) / 256, 256, 0, stream>>>(x, xhi, xlo, N1 * D / 4);
    pack_wt<<<256, 512, 0, stream>>>(Wl0, Wr0, WThi0, WTlo0);
    pack_wt<<<256, 512, 0, stream>>>(Wl1, Wr1, WThi1, WTlo1);

    fill_edges<<<(E0 + 255) / 256, 256, 0, stream>>>(src0, dst0, cnt0, eidx0, E0);
    aggregate_s<0><<<(N1 + 3) / 4, 256, 0, stream>>>(x, nullptr, cnt0, eidx0, agg0hi, agg0lo, N1);
    gemm_split<0><<<dim3((N1 + BM - 1) / BM, 2), 256, 0, stream>>>(
        agg0hi, agg0lo, xhi, xlo, WThi0, WTlo0, bl0, h0hi, h0lo, (float*)nullptr, N1);

    fill_edges<<<(E1 + 255) / 256, 256, 0, stream>>>(src1, dst1, cnt1, eidx1, E1);
    aggregate_s<1><<<(N2 + 3) / 4, 256, 0, stream>>>(h0hi, h0lo, cnt1, eidx1, agg1hi, agg1lo, N2);
    gemm_split<1><<<dim3((N2 + BM - 1) / BM, 2), 256, 0, stream>>>(
        agg1hi, agg1lo, h0hi, h0lo, WThi1, WTlo1, bl1,
        (unsigned short*)nullptr, (unsigned short*)nullptr, h1f, N2);

    final_softmax<<<(N2 + FS_ROWS - 1) / FS_ROWS, 256, 0, stream>>>(
        h1f, Wlin, blin, (float*)d_out, N2);
}

// Round 16
// 341.415 us; speedup vs baseline: 1.1227x; 1.0917x over previous
//
#include <hip/hip_runtime.h>
#include <math.h>

#define N0 200000
#define N1 50000
#define N2 10000
#define E0 750000
#define E1 150000
#define D 256
#define OUT 64
#define CAP 64

#define BM 64
#define BN 128
#define FS_ROWS 32

typedef unsigned int uint32;
using short8 = __attribute__((ext_vector_type(8))) short;
using f32x4 = __attribute__((ext_vector_type(4))) float;

// ---- bf16 split helpers: v ~ bf16(hi) + bf16(lo) ----
__device__ __forceinline__ unsigned short bf16_rne(float f) {
    unsigned int u = __float_as_uint(f);
    unsigned int r = (u + 0x7FFFu + ((u >> 16) & 1u)) >> 16;
    return (unsigned short)r;
}
__device__ __forceinline__ float bf16_f32(unsigned short h) {
    return __uint_as_float(((unsigned int)h) << 16);
}

// direct global->LDS copy, 16B per lane. LDS dest = wave-uniform base + lane*16.
__device__ __forceinline__ void gload_lds16(const void* g, void* l) {
    __builtin_amdgcn_global_load_lds(
        (const __attribute__((address_space(1))) unsigned int*)g,
        (__attribute__((address_space(3))) unsigned int*)l, 16, 0, 0);
}

// ---------------------------------------------------------------------------
// Build per-target edge lists (capacity CAP per target; max degree ~38).
// ---------------------------------------------------------------------------
__global__ void fill_edges(const int* __restrict__ src, const int* __restrict__ dst,
                           int* __restrict__ cnt, int* __restrict__ eidx, int E) {
    int e = blockIdx.x * blockDim.x + threadIdx.x;
    if (e >= E) return;
    int d = dst[e];
    int pos = atomicAdd(&cnt[d], 1);
    if (pos < CAP) eidx[d * CAP + pos] = src[e];
}

// ---------------------------------------------------------------------------
// Split fp32 -> (hi bf16, lo bf16) planes. 4 elems/thread.
// ---------------------------------------------------------------------------
__global__ void split_f32(const float* __restrict__ in, unsigned short* __restrict__ hi,
                          unsigned short* __restrict__ lo, int n4) {
    int i = blockIdx.x * blockDim.x + threadIdx.x;
    if (i >= n4) return;
    float4 v = *reinterpret_cast<const float4*>(in + (size_t)i * 4);
    ushort4 h, l;
    h.x = bf16_rne(v.x); l.x = bf16_rne(v.x - bf16_f32(h.x));
    h.y = bf16_rne(v.y); l.y = bf16_rne(v.y - bf16_f32(h.y));
    h.z = bf16_rne(v.z); l.z = bf16_rne(v.z - bf16_f32(h.z));
    h.w = bf16_rne(v.w); l.w = bf16_rne(v.w - bf16_f32(h.w));
    *reinterpret_cast<ushort4*>(hi + (size_t)i * 4) = h;
    *reinterpret_cast<ushort4*>(lo + (size_t)i * 4) = l;
}

// ---------------------------------------------------------------------------
// Pack W transposed+split: WThi/WTlo[n][kc] (kc<256 -> Wl[kc][n], else Wr).
// ---------------------------------------------------------------------------
__global__ void pack_wt(const float* __restrict__ Wl, const float* __restrict__ Wr,
                        unsigned short* __restrict__ WThi, unsigned short* __restrict__ WTlo) {
    int n = blockIdx.x;
    int kc = threadIdx.x;
    float v = (kc < 256) ? Wl[(size_t)kc * D + n] : Wr[(size_t)(kc - 256) * D + n];
    unsigned short h = bf16_rne(v);
    WThi[(size_t)n * 512 + kc] = h;
    WTlo[(size_t)n * 512 + kc] = bf16_rne(v - bf16_f32(h));
}

// ---------------------------------------------------------------------------
// Mean-aggregate neighbor rows from a bf16-HI plane only (512 B/row, halves
// the gather bytes vs fp32 — round-15 change: the aggregate is at the
// per-CU byte-delivery ceiling, so bytes ~= time). Precision: bf16 rounding
// of neighbors -> mean /sqrt(deg) -> dot damping; est. output absmax ~2e-4
// vs 6.05e-4 threshold. Output: split hi/lo planes (fp32 accumulate).
// ---------------------------------------------------------------------------
__global__ void aggregate_h(const unsigned short* __restrict__ srcHi,
                            const int* __restrict__ cnt, const int* __restrict__ eidx,
                            unsigned short* __restrict__ aggHi, unsigned short* __restrict__ aggLo,
                            int T) {
    int wave = threadIdx.x >> 6;
    int lane = threadIdx.x & 63;
    int t = blockIdx.x * 4 + wave;
    if (t >= T) return;
    int deg = cnt[t];
    int n = deg < CAP ? deg : CAP;
    int vidx = eidx[(size_t)t * CAP + lane];
    float a0 = 0.f, a1 = 0.f, a2 = 0.f, a3 = 0.f;

    for (int j0 = 0; j0 < n; j0 += 4) {
        int   s[4];
        float w[4];
        #pragma unroll
        for (int jj = 0; jj < 4; ++jj) {
            int j = j0 + jj;
            int sv = __shfl(vidx, j);
            bool act = j < n;
            s[jj] = act ? sv : 0;
            w[jj] = act ? 1.f : 0.f;
        }
        ushort4 uh[4];
        #pragma unroll
        for (int jj = 0; jj < 4; ++jj)
            uh[jj] = *reinterpret_cast<const ushort4*>(srcHi + (size_t)s[jj] * D + lane * 4);
        #pragma unroll
        for (int jj = 0; jj < 4; ++jj) {
            a0 += w[jj] * bf16_f32(uh[jj].x);
            a1 += w[jj] * bf16_f32(uh[jj].y);
            a2 += w[jj] * bf16_f32(uh[jj].z);
            a3 += w[jj] * bf16_f32(uh[jj].w);
        }
    }

    float sc = deg > 0 ? 1.0f / (float)deg : 0.0f;
    a0 *= sc; a1 *= sc; a2 *= sc; a3 *= sc;
    ushort4 oh, ol;
    oh.x = bf16_rne(a0); ol.x = bf16_rne(a0 - bf16_f32(oh.x));
    oh.y = bf16_rne(a1); ol.y = bf16_rne(a1 - bf16_f32(oh.y));
    oh.z = bf16_rne(a2); ol.z = bf16_rne(a2 - bf16_f32(oh.z));
    oh.w = bf16_rne(a3); ol.w = bf16_rne(a3 - bf16_f32(oh.w));
    *reinterpret_cast<ushort4*>(aggHi + (size_t)t * D + lane * 4) = oh;
    *reinterpret_cast<ushort4*>(aggLo + (size_t)t * D + lane * 4) = ol;
}

// ---------------------------------------------------------------------------
// Split-bf16 MFMA GEMM, 64x128 tile, BK=64, 1-PHASE (round-11 version —
// best measured; r12 B-from-global and r13/r15 2-phase dbuf both regressed:
// implicit wave-level overlap at 3 blocks/CU already hides staging).
// gload_lds w16 + pre-swizzled source + XOR read addressing (verified).
// ---------------------------------------------------------------------------
template<int ACT>
__global__ void __launch_bounds__(256, 3)
gemm_split(const unsigned short* __restrict__ A1hi, const unsigned short* __restrict__ A1lo,
           const unsigned short* __restrict__ A2hi, const unsigned short* __restrict__ A2lo,
           const unsigned short* __restrict__ WThi, const unsigned short* __restrict__ WTlo,
           const float* __restrict__ bias, unsigned short* __restrict__ Chi,
           unsigned short* __restrict__ Clo, float* __restrict__ Cf, int M) {
    __shared__ __align__(16) char sAhi[BM * 128];   //  8 KB
    __shared__ __align__(16) char sAlo[BM * 128];   //  8 KB
    __shared__ __align__(16) char sBhi[BN * 128];   // 16 KB
    __shared__ __align__(16) char sBlo[BN * 128];   // 16 KB

    const int tid = threadIdx.x;
    const int m0 = blockIdx.x * BM;
    const int n0 = blockIdx.y * BN;
    const int wid = tid >> 6, lane = tid & 63;
    const int lr = lane & 15;
    const int hi2 = lane >> 4;

    const int srow = lane >> 3;                    // row within 8-row chunk
    const int scol = ((lane & 7) ^ srow) << 4;     // pre-swizzled source byte col

    f32x4 acc[4][2];
    #pragma unroll
    for (int i = 0; i < 4; ++i)
        #pragma unroll
        for (int j = 0; j < 2; ++j)
            acc[i][j] = (f32x4){0.f, 0.f, 0.f, 0.f};

    for (int k0 = 0; k0 < 512; k0 += 64) {
        if (k0) __syncthreads();   // prior compute done before LDS overwrite
        const char* Ah = (const char*)((k0 < 256) ? A1hi : A2hi);
        const char* Al = (const char*)((k0 < 256) ? A1lo : A2lo);
        const int kc = k0 & 255;
        // A: 8 chunks of 8 rows, 2 per wave
        #pragma unroll
        for (int i = 0; i < 2; ++i) {
            int ch = wid * 2 + i;
            int row = ch * 8 + srow;
            size_t ga = ((size_t)(m0 + row) * D + kc) * 2 + scol;
            gload_lds16(Ah + ga, sAhi + ch * 1024);
            gload_lds16(Al + ga, sAlo + ch * 1024);
        }
        // B: 16 chunks of 8 rows, 4 per wave
        #pragma unroll
        for (int i = 0; i < 4; ++i) {
            int ch = wid * 4 + i;
            int row = ch * 8 + srow;
            size_t gb = ((size_t)(n0 + row) * 512 + k0) * 2 + scol;
            gload_lds16((const char*)WThi + gb, sBhi + ch * 1024);
            gload_lds16((const char*)WTlo + gb, sBlo + ch * 1024);
        }
        __syncthreads();   // vmcnt(0) drained by compiler before barrier

        #pragma unroll
        for (int slab = 0; slab < 2; ++slab) {
            const int z = slab * 64 + hi2 * 16;
            short8 ah[4], al[4], bh[2], bl[2];
            #pragma unroll
            for (int f = 0; f < 4; ++f) {
                int ra = f * 16 + lr;
                int oa = ra * 128 + (z ^ ((ra & 7) << 4));
                ah[f] = *reinterpret_cast<const short8*>(sAhi + oa);
                al[f] = *reinterpret_cast<const short8*>(sAlo + oa);
            }
            #pragma unroll
            for (int f = 0; f < 2; ++f) {
                int rb = wid * 32 + f * 16 + lr;
                int ob = rb * 128 + (z ^ ((rb & 7) << 4));
                bh[f] = *reinterpret_cast<const short8*>(sBhi + ob);
                bl[f] = *reinterpret_cast<const short8*>(sBlo + ob);
            }
            #pragma unroll
            for (int i = 0; i < 4; ++i)
                #pragma unroll
                for (int j = 0; j < 2; ++j) {
                    acc[i][j] = __builtin_amdgcn_mfma_f32_16x16x32_bf16(ah[i], bh[j], acc[i][j], 0, 0, 0);
                    acc[i][j] = __builtin_amdgcn_mfma_f32_16x16x32_bf16(ah[i], bl[j], acc[i][j], 0, 0, 0);
                    acc[i][j] = __builtin_amdgcn_mfma_f32_16x16x32_bf16(al[i], bh[j], acc[i][j], 0, 0, 0);
                }
        }
    }

    // epilogue: D[row][col], col = lane&15, row = (lane>>4)*4 + reg
    #pragma unroll
    for (int fn = 0; fn < 2; ++fn) {
        int col = n0 + wid * 32 + fn * 16 + lr;
        float bv = bias[col];
        #pragma unroll
        for (int fm = 0; fm < 4; ++fm) {
            int rbase = m0 + fm * 16 + hi2 * 4;
            #pragma unroll
            for (int r = 0; r < 4; ++r) {
                int m = rbase + r;
                if (m < M) {
                    float v = acc[fm][fn][r] + bv;
                    if (ACT == 0) {
                        v = fmaxf(v, 0.f);
                        unsigned short h = bf16_rne(v);
                        Chi[(size_t)m * D + col] = h;
                        Clo[(size_t)m * D + col] = bf16_rne(v - bf16_f32(h));
                    } else {
                        Cf[(size_t)m * D + col] = tanhf(v);
                    }
                }
            }
        }
    }
}

// ---------------------------------------------------------------------------
// Final: out[M][64] = softmax(H @ Wlin + blin).
// Wlin in LDS once/block; H via wave-uniform scalar loads; 4 independent
// partial accumulators (chain = fma latency only).
// ---------------------------------------------------------------------------
__global__ void __launch_bounds__(256)
final_softmax(const float* __restrict__ H, const float* __restrict__ Wlin,
              const float* __restrict__ blin, float* __restrict__ out, int M) {
    __shared__ __align__(16) float sW[D * OUT];   // 64 KB
    const int tid = threadIdx.x;
    #pragma unroll
    for (int i = 0; i < 16; ++i) {
        int idx = (i * 256 + tid) * 4;
        *reinterpret_cast<float4*>(&sW[idx]) = *reinterpret_cast<const float4*>(&Wlin[idx]);
    }
    __syncthreads();

    const int wave = tid >> 6, lane = tid & 63;
    const float bl = blin[lane];
    int r0 = blockIdx.x * FS_ROWS + wave * (FS_ROWS / 4);
    int r1 = r0 + FS_ROWS / 4;
    for (int r = r0; r < r1 && r < M; ++r) {
        const float* hrow = H + (size_t)r * D;   // wave-uniform -> scalar loads
        float a0 = 0.f, a1 = 0.f, a2 = 0.f, a3 = 0.f;
        #pragma unroll 8
        for (int k = 0; k < D; k += 4) {
            a0 += hrow[k + 0] * sW[(k + 0) * OUT + lane];
            a1 += hrow[k + 1] * sW[(k + 1) * OUT + lane];
            a2 += hrow[k + 2] * sW[(k + 2) * OUT + lane];
            a3 += hrow[k + 3] * sW[(k + 3) * OUT + lane];
        }
        float acc = (a0 + a1) + (a2 + a3) + bl;
        float mx = acc;
        #pragma unroll
        for (int off = 32; off > 0; off >>= 1) mx = fmaxf(mx, __shfl_xor(mx, off));
        float e = __expf(acc - mx);
        float s = e;
        #pragma unroll
        for (int off = 32; off > 0; off >>= 1) s += __shfl_xor(s, off);
        out[(size_t)r * OUT + lane] = e / s;
    }
}

extern "C" void kernel_launch(void* const* d_in, const int* in_sizes, int n_in,
                              void* d_out, int out_size, void* d_ws, size_t ws_size,
                              hipStream_t stream) {
    const float* x    = (const float*)d_in[0];
    const int*   src0 = (const int*)d_in[1];
    const int*   dst0 = (const int*)d_in[2];
    const int*   src1 = (const int*)d_in[3];
    const int*   dst1 = (const int*)d_in[4];
    const float* Wl0  = (const float*)d_in[5];
    const float* bl0  = (const float*)d_in[6];
    const float* Wr0  = (const float*)d_in[7];
    const float* Wl1  = (const float*)d_in[8];
    const float* bl1  = (const float*)d_in[9];
    const float* Wr1  = (const float*)d_in[10];
    const float* Wlin = (const float*)d_in[11];
    const float* blin = (const float*)d_in[12];

    const int PADX = 200064;  // x split: all N0 rows (gather sources span N0), 64-row mult
    const int PAD1 = 50048;   // 782*64 (gload_lds reads unmasked -> pad rows)
    const int PAD2 = 10112;   // 158*64

    char* ws = (char*)d_ws;
    size_t off = 0;
    auto alloc = [&](size_t bytes) {
        void* p = ws + off;
        off += (bytes + 255) & ~(size_t)255;
        return p;
    };
    int* cnt0  = (int*)alloc((size_t)N1 * 4);
    int* eidx0 = (int*)alloc((size_t)N1 * CAP * 4);
    int* cnt1  = (int*)alloc((size_t)N2 * 4);
    int* eidx1 = (int*)alloc((size_t)N2 * CAP * 4);
    unsigned short* agg0hi = (unsigned short*)alloc((size_t)PAD1 * D * 2);
    unsigned short* agg0lo = (unsigned short*)alloc((size_t)PAD1 * D * 2);
    unsigned short* xhi    = (unsigned short*)alloc((size_t)PADX * D * 2);
    unsigned short* xlo    = (unsigned short*)alloc((size_t)PADX * D * 2);
    unsigned short* h0hi   = (unsigned short*)alloc((size_t)N1 * D * 2);
    unsigned short* h0lo   = (unsigned short*)alloc((size_t)N1 * D * 2);
    unsigned short* agg1hi = (unsigned short*)alloc((size_t)PAD2 * D * 2);
    unsigned short* agg1lo = (unsigned short*)alloc((size_t)PAD2 * D * 2);
    float* h1f = (float*)alloc((size_t)N2 * D * 4);
    unsigned short* WThi0 = (unsigned short*)alloc((size_t)D * 512 * 2);
    unsigned short* WTlo0 = (unsigned short*)alloc((size_t)D * 512 * 2);
    unsigned short* WThi1 = (unsigned short*)alloc((size_t)D * 512 * 2);
    unsigned short* WTlo1 = (unsigned short*)alloc((size_t)D * 512 * 2);

    hipMemsetAsync(cnt0, 0, (size_t)N1 * 4, stream);
    hipMemsetAsync(cnt1, 0, (size_t)N2 * 4, stream);

    // split ALL of x (N0 rows): gather sources span [0, N0); gemm A2 uses rows < N1.
    split_f32<<<(N0 * (D / 4) + 255) / 256, 256, 0, stream>>>(x, xhi, xlo, N0 * (D / 4));
    pack_wt<<<256, 512, 0, stream>>>(Wl0, Wr0, WThi0, WTlo0);
    pack_wt<<<256, 512, 0, stream>>>(Wl1, Wr1, WThi1, WTlo1);

    fill_edges<<<(E0 + 255) / 256, 256, 0, stream>>>(src0, dst0, cnt0, eidx0, E0);
    aggregate_h<<<(N1 + 3) / 4, 256, 0, stream>>>(xhi, cnt0, eidx0, agg0hi, agg0lo, N1);
    gemm_split<0><<<dim3((N1 + BM - 1) / BM, 2), 256, 0, stream>>>(
        agg0hi, agg0lo, xhi, xlo, WThi0, WTlo0, bl0, h0hi, h0lo, (float*)nullptr, N1);

    fill_edges<<<(E1 + 255) / 256, 256, 0, stream>>>(src1, dst1, cnt1, eidx1, E1);
    aggregate_h<<<(N2 + 3) / 4, 256, 0, stream>>>(h0hi, cnt1, eidx1, agg1hi, agg1lo, N2);
    gemm_split<1><<<dim3((N2 + BM - 1) / BM, 2), 256, 0, stream>>>(
        agg1hi, agg1lo, h0hi, h0lo, WThi1, WTlo1, bl1,
        (unsigned short*)nullptr, (unsigned short*)nullptr, h1f, N2);

    final_softmax<<<(N2 + FS_ROWS - 1) / FS_ROWS, 256, 0, stream>>>(
        h1f, Wlin, blin, (float*)d_out, N2);
}

// Round 18
// 291.311 us; speedup vs baseline: 1.3158x; 1.1720x over previous
//
#include <hip/hip_runtime.h>
#include <math.h>

#define N0 200000
#define N1 50000
#define N2 10000
#define E0 750000
#define E1 150000
#define D 256
#define OUT 64
#define CAP 64

#define BM 64
#define BN 128
#define FS_ROWS 32

typedef unsigned int uint32;
using short8 = __attribute__((ext_vector_type(8))) short;
using f32x4 = __attribute__((ext_vector_type(4))) float;

// ---- bf16 helpers ----
__device__ __forceinline__ unsigned short bf16_rne(float f) {
    unsigned int u = __float_as_uint(f);
    unsigned int r = (u + 0x7FFFu + ((u >> 16) & 1u)) >> 16;
    return (unsigned short)r;
}
__device__ __forceinline__ float bf16_f32(unsigned short h) {
    return __uint_as_float(((unsigned int)h) << 16);
}

// direct global->LDS copy, 16B per lane. LDS dest = wave-uniform base + lane*16.
__device__ __forceinline__ void gload_lds16(const void* g, void* l) {
    __builtin_amdgcn_global_load_lds(
        (const __attribute__((address_space(1))) unsigned int*)g,
        (__attribute__((address_space(3))) unsigned int*)l, 16, 0, 0);
}

// ---------------------------------------------------------------------------
// Build per-target edge lists (capacity CAP per target; max degree ~38).
// ---------------------------------------------------------------------------
__global__ void fill_edges(const int* __restrict__ src, const int* __restrict__ dst,
                           int* __restrict__ cnt, int* __restrict__ eidx, int E) {
    int e = blockIdx.x * blockDim.x + threadIdx.x;
    if (e >= E) return;
    int d = dst[e];
    int pos = atomicAdd(&cnt[d], 1);
    if (pos < CAP) eidx[d * CAP + pos] = src[e];
}

// ---------------------------------------------------------------------------
// Cast fp32 -> bf16 (hi plane only). Round-17: A-side is bf16-only; the
// bf16 comparison floor (absmax pinned at 1 ulp across r2..r16) shows the
// threshold has ~5x headroom for this.
// ---------------------------------------------------------------------------
__global__ void cast_hi(const float* __restrict__ in, unsigned short* __restrict__ hi, int n4) {
    int i = blockIdx.x * blockDim.x + threadIdx.x;
    if (i >= n4) return;
    float4 v = *reinterpret_cast<const float4*>(in + (size_t)i * 4);
    ushort4 h;
    h.x = bf16_rne(v.x); h.y = bf16_rne(v.y);
    h.z = bf16_rne(v.z); h.w = bf16_rne(v.w);
    *reinterpret_cast<ushort4*>(hi + (size_t)i * 4) = h;
}

// ---------------------------------------------------------------------------
// Pack W transposed+split: WThi/WTlo[n][kc] (kc<256 -> Wl[kc][n], else Wr).
// W keeps hi+lo (near-fp32); A side is bf16-only.
// ---------------------------------------------------------------------------
__global__ void pack_wt(const float* __restrict__ Wl, const float* __restrict__ Wr,
                        unsigned short* __restrict__ WThi, unsigned short* __restrict__ WTlo) {
    int n = blockIdx.x;
    int kc = threadIdx.x;
    float v = (kc < 256) ? Wl[(size_t)kc * D + n] : Wr[(size_t)(kc - 256) * D + n];
    unsigned short h = bf16_rne(v);
    WThi[(size_t)n * 512 + kc] = h;
    WTlo[(size_t)n * 512 + kc] = bf16_rne(v - bf16_f32(h));
}

// ---------------------------------------------------------------------------
// Mean-aggregate neighbor rows from a bf16 plane (512 B/row — at the per-CU
// byte-delivery ceiling, bytes ~= time). fp32 accumulate, bf16 output.
// ---------------------------------------------------------------------------
__global__ void aggregate_h(const unsigned short* __restrict__ srcHi,
                            const int* __restrict__ cnt, const int* __restrict__ eidx,
                            unsigned short* __restrict__ aggHi, int T) {
    int wave = threadIdx.x >> 6;
    int lane = threadIdx.x & 63;
    int t = blockIdx.x * 4 + wave;
    if (t >= T) return;
    int deg = cnt[t];
    int n = deg < CAP ? deg : CAP;
    int vidx = eidx[(size_t)t * CAP + lane];
    float a0 = 0.f, a1 = 0.f, a2 = 0.f, a3 = 0.f;

    for (int j0 = 0; j0 < n; j0 += 4) {
        int   s[4];
        float w[4];
        #pragma unroll
        for (int jj = 0; jj < 4; ++jj) {
            int j = j0 + jj;
            int sv = __shfl(vidx, j);
            bool act = j < n;
            s[jj] = act ? sv : 0;
            w[jj] = act ? 1.f : 0.f;
        }
        ushort4 uh[4];
        #pragma unroll
        for (int jj = 0; jj < 4; ++jj)
            uh[jj] = *reinterpret_cast<const ushort4*>(srcHi + (size_t)s[jj] * D + lane * 4);
        #pragma unroll
        for (int jj = 0; jj < 4; ++jj) {
            a0 += w[jj] * bf16_f32(uh[jj].x);
            a1 += w[jj] * bf16_f32(uh[jj].y);
            a2 += w[jj] * bf16_f32(uh[jj].z);
            a3 += w[jj] * bf16_f32(uh[jj].w);
        }
    }

    float sc = deg > 0 ? 1.0f / (float)deg : 0.0f;
    ushort4 oh;
    oh.x = bf16_rne(a0 * sc); oh.y = bf16_rne(a1 * sc);
    oh.z = bf16_rne(a2 * sc); oh.w = bf16_rne(a3 * sc);
    *reinterpret_cast<ushort4*>(aggHi + (size_t)t * D + lane * 4) = oh;
}

// ---------------------------------------------------------------------------
// MFMA GEMM: C[M][256] = act([A1|A2] @ (Whi+Wlo) + bias), K=512.
// A bf16-only (round-17): 2 MFMA terms (Ahi*Whi + Ahi*Wlo) — 2/3 the MFMA
// work of the 3-term split, half the A staging, LDS 40 KB (3 blocks/CU).
// 1-phase r11 schedule (best measured; dbuf r13/r15 and B-from-global r12
// both regressed). gload_lds w16 + pre-swizzled source + XOR reads.
// ACT 0: relu -> bf16 store. ACT 1: tanh -> fp32 store.
// ---------------------------------------------------------------------------
template<int ACT>
__global__ void __launch_bounds__(256, 3)
gemm_split(const unsigned short* __restrict__ A1hi, const unsigned short* __restrict__ A2hi,
           const unsigned short* __restrict__ WThi, const unsigned short* __restrict__ WTlo,
           const float* __restrict__ bias, unsigned short* __restrict__ Chi,
           float* __restrict__ Cf, int M) {
    __shared__ __align__(16) char sAhi[BM * 128];   //  8 KB
    __shared__ __align__(16) char sBhi[BN * 128];   // 16 KB
    __shared__ __align__(16) char sBlo[BN * 128];   // 16 KB

    const int tid = threadIdx.x;
    const int m0 = blockIdx.x * BM;
    const int n0 = blockIdx.y * BN;
    const int wid = tid >> 6, lane = tid & 63;
    const int lr = lane & 15;
    const int hi2 = lane >> 4;

    const int srow = lane >> 3;                    // row within 8-row chunk
    const int scol = ((lane & 7) ^ srow) << 4;     // pre-swizzled source byte col

    f32x4 acc[4][2];
    #pragma unroll
    for (int i = 0; i < 4; ++i)
        #pragma unroll
        for (int j = 0; j < 2; ++j)
            acc[i][j] = (f32x4){0.f, 0.f, 0.f, 0.f};

    for (int k0 = 0; k0 < 512; k0 += 64) {
        if (k0) __syncthreads();   // prior compute done before LDS overwrite
        const char* Ah = (const char*)((k0 < 256) ? A1hi : A2hi);
        const int kc = k0 & 255;
        // A: 8 chunks of 8 rows, 2 per wave (hi plane only)
        #pragma unroll
        for (int i = 0; i < 2; ++i) {
            int ch = wid * 2 + i;
            int row = ch * 8 + srow;
            size_t ga = ((size_t)(m0 + row) * D + kc) * 2 + scol;
            gload_lds16(Ah + ga, sAhi + ch * 1024);
        }
        // B: 16 chunks of 8 rows, 4 per wave, hi+lo planes
        #pragma unroll
        for (int i = 0; i < 4; ++i) {
            int ch = wid * 4 + i;
            int row = ch * 8 + srow;
            size_t gb = ((size_t)(n0 + row) * 512 + k0) * 2 + scol;
            gload_lds16((const char*)WThi + gb, sBhi + ch * 1024);
            gload_lds16((const char*)WTlo + gb, sBlo + ch * 1024);
        }
        __syncthreads();   // vmcnt(0) drained by compiler before barrier

        #pragma unroll
        for (int slab = 0; slab < 2; ++slab) {
            const int z = slab * 64 + hi2 * 16;
            short8 ah[4], bh[2], bl[2];
            #pragma unroll
            for (int f = 0; f < 4; ++f) {
                int ra = f * 16 + lr;
                int oa = ra * 128 + (z ^ ((ra & 7) << 4));
                ah[f] = *reinterpret_cast<const short8*>(sAhi + oa);
            }
            #pragma unroll
            for (int f = 0; f < 2; ++f) {
                int rb = wid * 32 + f * 16 + lr;
                int ob = rb * 128 + (z ^ ((rb & 7) << 4));
                bh[f] = *reinterpret_cast<const short8*>(sBhi + ob);
                bl[f] = *reinterpret_cast<const short8*>(sBlo + ob);
            }
            #pragma unroll
            for (int i = 0; i < 4; ++i)
                #pragma unroll
                for (int j = 0; j < 2; ++j) {
                    acc[i][j] = __builtin_amdgcn_mfma_f32_16x16x32_bf16(ah[i], bh[j], acc[i][j], 0, 0, 0);
                    acc[i][j] = __builtin_amdgcn_mfma_f32_16x16x32_bf16(ah[i], bl[j], acc[i][j], 0, 0, 0);
                }
        }
    }

    // epilogue: D[row][col], col = lane&15, row = (lane>>4)*4 + reg
    #pragma unroll
    for (int fn = 0; fn < 2; ++fn) {
        int col = n0 + wid * 32 + fn * 16 + lr;
        float bv = bias[col];
        #pragma unroll
        for (int fm = 0; fm < 4; ++fm) {
            int rbase = m0 + fm * 16 + hi2 * 4;
            #pragma unroll
            for (int r = 0; r < 4; ++r) {
                int m = rbase + r;
                if (m < M) {
                    float v = acc[fm][fn][r] + bv;
                    if (ACT == 0) {
                        Chi[(size_t)m * D + col] = bf16_rne(fmaxf(v, 0.f));
                    } else {
                        Cf[(size_t)m * D + col] = tanhf(v);
                    }
                }
            }
        }
    }
}

// ---------------------------------------------------------------------------
// Final: out[M][64] = softmax(H @ Wlin + blin).
// Wlin in LDS once/block; H via wave-uniform scalar loads; 4 independent
// partial accumulators (chain = fma latency only).
// ---------------------------------------------------------------------------
__global__ void __launch_bounds__(256)
final_softmax(const float* __restrict__ H, const float* __restrict__ Wlin,
              const float* __restrict__ blin, float* __restrict__ out, int M) {
    __shared__ __align__(16) float sW[D * OUT];   // 64 KB
    const int tid = threadIdx.x;
    #pragma unroll
    for (int i = 0; i < 16; ++i) {
        int idx = (i * 256 + tid) * 4;
        *reinterpret_cast<float4*>(&sW[idx]) = *reinterpret_cast<const float4*>(&Wlin[idx]);
    }
    __syncthreads();

    const int wave = tid >> 6, lane = tid & 63;
    const float bl = blin[lane];
    int r0 = blockIdx.x * FS_ROWS + wave * (FS_ROWS / 4);
    int r1 = r0 + FS_ROWS / 4;
    for (int r = r0; r < r1 && r < M; ++r) {
        const float* hrow = H + (size_t)r * D;   // wave-uniform -> scalar loads
        float a0 = 0.f, a1 = 0.f, a2 = 0.f, a3 = 0.f;
        #pragma unroll 8
        for (int k = 0; k < D; k += 4) {
            a0 += hrow[k + 0] * sW[(k + 0) * OUT + lane];
            a1 += hrow[k + 1] * sW[(k + 1) * OUT + lane];
            a2 += hrow[k + 2] * sW[(k + 2) * OUT + lane];
            a3 += hrow[k + 3] * sW[(k + 3) * OUT + lane];
        }
        float acc = (a0 + a1) + (a2 + a3) + bl;
        float mx = acc;
        #pragma unroll
        for (int off = 32; off > 0; off >>= 1) mx = fmaxf(mx, __shfl_xor(mx, off));
        float e = __expf(acc - mx);
        float s = e;
        #pragma unroll
        for (int off = 32; off > 0; off >>= 1) s += __shfl_xor(s, off);
        out[(size_t)r * OUT + lane] = e / s;
    }
}

extern "C" void kernel_launch(void* const* d_in, const int* in_sizes, int n_in,
                              void* d_out, int out_size, void* d_ws, size_t ws_size,
                              hipStream_t stream) {
    const float* x    = (const float*)d_in[0];
    const int*   src0 = (const int*)d_in[1];
    const int*   dst0 = (const int*)d_in[2];
    const int*   src1 = (const int*)d_in[3];
    const int*   dst1 = (const int*)d_in[4];
    const float* Wl0  = (const float*)d_in[5];
    const float* bl0  = (const float*)d_in[6];
    const float* Wr0  = (const float*)d_in[7];
    const float* Wl1  = (const float*)d_in[8];
    const float* bl1  = (const float*)d_in[9];
    const float* Wr1  = (const float*)d_in[10];
    const float* Wlin = (const float*)d_in[11];
    const float* blin = (const float*)d_in[12];

    const int PADX = 200064;  // xhi: all N0 rows (gather sources span N0), 64-row mult
    const int PAD1 = 50048;   // 782*64 (gload_lds reads unmasked -> pad rows)
    const int PAD2 = 10112;   // 158*64

    char* ws = (char*)d_ws;
    size_t off = 0;
    auto alloc = [&](size_t bytes) {
        void* p = ws + off;
        off += (bytes + 255) & ~(size_t)255;
        return p;
    };
    int* cnt0  = (int*)alloc((size_t)N1 * 4);
    int* eidx0 = (int*)alloc((size_t)N1 * CAP * 4);
    int* cnt1  = (int*)alloc((size_t)N2 * 4);
    int* eidx1 = (int*)alloc((size_t)N2 * CAP * 4);
    unsigned short* agg0hi = (unsigned short*)alloc((size_t)PAD1 * D * 2);
    unsigned short* xhi    = (unsigned short*)alloc((size_t)PADX * D * 2);
    unsigned short* h0hi   = (unsigned short*)alloc((size_t)N1 * D * 2);
    unsigned short* agg1hi = (unsigned short*)alloc((size_t)PAD2 * D * 2);
    float* h1f = (float*)alloc((size_t)N2 * D * 4);
    unsigned short* WThi0 = (unsigned short*)alloc((size_t)D * 512 * 2);
    unsigned short* WTlo0 = (unsigned short*)alloc((size_t)D * 512 * 2);
    unsigned short* WThi1 = (unsigned short*)alloc((size_t)D * 512 * 2);
    unsigned short* WTlo1 = (unsigned short*)alloc((size_t)D * 512 * 2);

    hipMemsetAsync(cnt0, 0, (size_t)N1 * 4, stream);
    hipMemsetAsync(cnt1, 0, (size_t)N2 * 4, stream);

    // cast ALL of x (N0 rows) to bf16: gather sources span [0, N0); gemm A2 uses rows < N1.
    cast_hi<<<(N0 * (D / 4) + 255) / 256, 256, 0, stream>>>(x, xhi, N0 * (D / 4));
    pack_wt<<<256, 512, 0, stream>>>(Wl0, Wr0, WThi0, WTlo0);
    pack_wt<<<256, 512, 0, stream>>>(Wl1, Wr1, WThi1, WTlo1);

    fill_edges<<<(E0 + 255) / 256, 256, 0, stream>>>(src0, dst0, cnt0, eidx0, E0);
    aggregate_h<<<(N1 + 3) / 4, 256, 0, stream>>>(xhi, cnt0, eidx0, agg0hi, N1);
    gemm_split<0><<<dim3((N1 + BM - 1) / BM, 2), 256, 0, stream>>>(
        agg0hi, xhi, WThi0, WTlo0, bl0, h0hi, (float*)nullptr, N1);

    fill_edges<<<(E1 + 255) / 256, 256, 0, stream>>>(src1, dst1, cnt1, eidx1, E1);
    aggregate_h<<<(N2 + 3) / 4, 256, 0, stream>>>(h0hi, cnt1, eidx1, agg1hi, N2);
    gemm_split<1><<<dim3((N2 + BM - 1) / BM, 2), 256, 0, stream>>>(
        agg1hi, h0hi, WThi1, WTlo1, bl1, (unsigned short*)nullptr, h1f, N2);

    final_softmax<<<(N2 + FS_ROWS - 1) / FS_ROWS, 256, 0, stream>>>(
        h1f, Wlin, blin, (float*)d_out, N2);
}

// Round 22
// 280.132 us; speedup vs baseline: 1.3683x; 1.0399x over previous
//
#include <hip/hip_runtime.h>
#include <math.h>

#define N0 200000
#define N1 50000
#define N2 10000
#define E0 750000
#define E1 150000
#define D 256
#define OUT 64
#define CAP 64

#define BM 64
#define BN 128
#define FS_ROWS 32

typedef unsigned int uint32;
using short8 = __attribute__((ext_vector_type(8))) short;
using f32x4 = __attribute__((ext_vector_type(4))) float;

// ---- bf16 helpers ----
__device__ __forceinline__ unsigned short bf16_rne(float f) {
    unsigned int u = __float_as_uint(f);
    unsigned int r = (u + 0x7FFFu + ((u >> 16) & 1u)) >> 16;
    return (unsigned short)r;
}
__device__ __forceinline__ float bf16_f32(unsigned short h) {
    return __uint_as_float(((unsigned int)h) << 16);
}

// direct global->LDS copy, 16B per lane. LDS dest = wave-uniform base + lane*16.
__device__ __forceinline__ void gload_lds16(const void* g, void* l) {
    __builtin_amdgcn_global_load_lds(
        (const __attribute__((address_space(1))) unsigned int*)g,
        (__attribute__((address_space(3))) unsigned int*)l, 16, 0, 0);
}

// ---------------------------------------------------------------------------
// Merged edge-list build for BOTH layers (one launch, round-19).
// ---------------------------------------------------------------------------
__global__ void fill_edges2(const int* __restrict__ src0, const int* __restrict__ dst0,
                            int* __restrict__ cnt0, int* __restrict__ eidx0,
                            const int* __restrict__ src1, const int* __restrict__ dst1,
                            int* __restrict__ cnt1, int* __restrict__ eidx1) {
    int e = blockIdx.x * blockDim.x + threadIdx.x;
    if (e < E0) {
        int d = dst0[e];
        int pos = atomicAdd(&cnt0[d], 1);
        if (pos < CAP) eidx0[d * CAP + pos] = src0[e];
    } else if (e < E0 + E1) {
        int e1 = e - E0;
        int d = dst1[e1];
        int pos = atomicAdd(&cnt1[d], 1);
        if (pos < CAP) eidx1[d * CAP + pos] = src1[e1];
    }
}

// ---------------------------------------------------------------------------
// Cast fp32 -> bf16 (hi plane only). A-side is bf16-only (r17/r18: absmax
// stayed pinned at the 1-ulp bf16 comparison floor).
// ---------------------------------------------------------------------------
__global__ void cast_hi(const float* __restrict__ in, unsigned short* __restrict__ hi, int n4) {
    int i = blockIdx.x * blockDim.x + threadIdx.x;
    if (i >= n4) return;
    float4 v = *reinterpret_cast<const float4*>(in + (size_t)i * 4);
    ushort4 h;
    h.x = bf16_rne(v.x); h.y = bf16_rne(v.y);
    h.z = bf16_rne(v.z); h.w = bf16_rne(v.w);
    *reinterpret_cast<ushort4*>(hi + (size_t)i * 4) = h;
}

// ---------------------------------------------------------------------------
// Pack BOTH layers' W transposed+split (one launch): blockIdx.y selects layer.
// WThi/WTlo[n][kc] (kc<256 -> Wl[kc][n], else Wr). W keeps hi+lo.
// ---------------------------------------------------------------------------
__global__ void pack_wt2(const float* __restrict__ Wl0, const float* __restrict__ Wr0,
                         unsigned short* __restrict__ WThi0, unsigned short* __restrict__ WTlo0,
                         const float* __restrict__ Wl1, const float* __restrict__ Wr1,
                         unsigned short* __restrict__ WThi1, unsigned short* __restrict__ WTlo1) {
    const float* Wl = blockIdx.y ? Wl1 : Wl0;
    const float* Wr = blockIdx.y ? Wr1 : Wr0;
    unsigned short* WThi = blockIdx.y ? WThi1 : WThi0;
    unsigned short* WTlo = blockIdx.y ? WTlo1 : WTlo0;
    int n = blockIdx.x;
    int kc = threadIdx.x;
    float v = (kc < 256) ? Wl[(size_t)kc * D + n] : Wr[(size_t)(kc - 256) * D + n];
    unsigned short h = bf16_rne(v);
    WThi[(size_t)n * 512 + kc] = h;
    WTlo[(size_t)n * 512 + kc] = bf16_rne(v - bf16_f32(h));
}

// ---------------------------------------------------------------------------
// Mean-aggregate neighbor rows from a bf16 plane (512 B/row — at the per-CU
// byte-delivery ceiling, bytes ~= time). fp32 accumulate, bf16 output.
// ---------------------------------------------------------------------------
__global__ void aggregate_h(const unsigned short* __restrict__ srcHi,
                            const int* __restrict__ cnt, const int* __restrict__ eidx,
                            unsigned short* __restrict__ aggHi, int T) {
    int wave = threadIdx.x >> 6;
    int lane = threadIdx.x & 63;
    int t = blockIdx.x * 4 + wave;
    if (t >= T) return;
    int deg = cnt[t];
    int n = deg < CAP ? deg : CAP;
    int vidx = eidx[(size_t)t * CAP + lane];
    float a0 = 0.f, a1 = 0.f, a2 = 0.f, a3 = 0.f;

    for (int j0 = 0; j0 < n; j0 += 4) {
        int   s[4];
        float w[4];
        #pragma unroll
        for (int jj = 0; jj < 4; ++jj) {
            int j = j0 + jj;
            int sv = __shfl(vidx, j);
            bool act = j < n;
            s[jj] = act ? sv : 0;
            w[jj] = act ? 1.f : 0.f;
        }
        ushort4 uh[4];
        #pragma unroll
        for (int jj = 0; jj < 4; ++jj)
            uh[jj] = *reinterpret_cast<const ushort4*>(srcHi + (size_t)s[jj] * D + lane * 4);
        #pragma unroll
        for (int jj = 0; jj < 4; ++jj) {
            a0 += w[jj] * bf16_f32(uh[jj].x);
            a1 += w[jj] * bf16_f32(uh[jj].y);
            a2 += w[jj] * bf16_f32(uh[jj].z);
            a3 += w[jj] * bf16_f32(uh[jj].w);
        }
    }

    float sc = deg > 0 ? 1.0f / (float)deg : 0.0f;
    ushort4 oh;
    oh.x = bf16_rne(a0 * sc); oh.y = bf16_rne(a1 * sc);
    oh.z = bf16_rne(a2 * sc); oh.w = bf16_rne(a3 * sc);
    *reinterpret_cast<ushort4*>(aggHi + (size_t)t * D + lane * 4) = oh;
}

// ---------------------------------------------------------------------------
// MFMA GEMM: C[M][256] = act([A1|A2] @ (Whi+Wlo) + bias), K=512.
// A bf16-only, 2 MFMA terms. LDS 40 KB -> round-19: __launch_bounds__(256,4)
// = 4 blocks/CU (160 KB exactly); whole 782-block grid co-resident in ONE
// round, deepening cross-block stage/MFMA overlap (the r11 mechanism).
// 1-phase schedule (best measured: dbuf r13/r15 and B-global r12 regressed).
// ---------------------------------------------------------------------------
template<int ACT>
__global__ void __launch_bounds__(256, 4)
gemm_split(const unsigned short* __restrict__ A1hi, const unsigned short* __restrict__ A2hi,
           const unsigned short* __restrict__ WThi, const unsigned short* __restrict__ WTlo,
           const float* __restrict__ bias, unsigned short* __restrict__ Chi,
           float* __restrict__ Cf, int M) {
    __shared__ __align__(16) char sAhi[BM * 128];   //  8 KB
    __shared__ __align__(16) char sBhi[BN * 128];   // 16 KB
    __shared__ __align__(16) char sBlo[BN * 128];   // 16 KB

    const int tid = threadIdx.x;
    const int m0 = blockIdx.x * BM;
    const int n0 = blockIdx.y * BN;
    const int wid = tid >> 6, lane = tid & 63;
    const int lr = lane & 15;
    const int hi2 = lane >> 4;

    const int srow = lane >> 3;                    // row within 8-row chunk
    const int scol = ((lane & 7) ^ srow) << 4;     // pre-swizzled source byte col

    f32x4 acc[4][2];
    #pragma unroll
    for (int i = 0; i < 4; ++i)
        #pragma unroll
        for (int j = 0; j < 2; ++j)
            acc[i][j] = (f32x4){0.f, 0.f, 0.f, 0.f};

    for (int k0 = 0; k0 < 512; k0 += 64) {
        if (k0) __syncthreads();   // prior compute done before LDS overwrite
        const char* Ah = (const char*)((k0 < 256) ? A1hi : A2hi);
        const int kc = k0 & 255;
        // A: 8 chunks of 8 rows, 2 per wave (hi plane only)
        #pragma unroll
        for (int i = 0; i < 2; ++i) {
            int ch = wid * 2 + i;
            int row = ch * 8 + srow;
            size_t ga = ((size_t)(m0 + row) * D + kc) * 2 + scol;
            gload_lds16(Ah + ga, sAhi + ch * 1024);
        }
        // B: 16 chunks of 8 rows, 4 per wave, hi+lo planes
        #pragma unroll
        for (int i = 0; i < 4; ++i) {
            int ch = wid * 4 + i;
            int row = ch * 8 + srow;
            size_t gb = ((size_t)(n0 + row) * 512 + k0) * 2 + scol;
            gload_lds16((const char*)WThi + gb, sBhi + ch * 1024);
            gload_lds16((const char*)WTlo + gb, sBlo + ch * 1024);
        }
        __syncthreads();   // vmcnt(0) drained by compiler before barrier

        #pragma unroll
        for (int slab = 0; slab < 2; ++slab) {
            const int z = slab * 64 + hi2 * 16;
            short8 ah[4], bh[2], bl[2];
            #pragma unroll
            for (int f = 0; f < 4; ++f) {
                int ra = f * 16 + lr;
                int oa = ra * 128 + (z ^ ((ra & 7) << 4));
                ah[f] = *reinterpret_cast<const short8*>(sAhi + oa);
            }
            #pragma unroll
            for (int f = 0; f < 2; ++f) {
                int rb = wid * 32 + f * 16 + lr;
                int ob = rb * 128 + (z ^ ((rb & 7) << 4));
                bh[f] = *reinterpret_cast<const short8*>(sBhi + ob);
                bl[f] = *reinterpret_cast<const short8*>(sBlo + ob);
            }
            #pragma unroll
            for (int i = 0; i < 4; ++i)
                #pragma unroll
                for (int j = 0; j < 2; ++j) {
                    acc[i][j] = __builtin_amdgcn_mfma_f32_16x16x32_bf16(ah[i], bh[j], acc[i][j], 0, 0, 0);
                    acc[i][j] = __builtin_amdgcn_mfma_f32_16x16x32_bf16(ah[i], bl[j], acc[i][j], 0, 0, 0);
                }
        }
    }

    // epilogue: D[row][col], col = lane&15, row = (lane>>4)*4 + reg
    #pragma unroll
    for (int fn = 0; fn < 2; ++fn) {
        int col = n0 + wid * 32 + fn * 16 + lr;
        float bv = bias[col];
        #pragma unroll
        for (int fm = 0; fm < 4; ++fm) {
            int rbase = m0 + fm * 16 + hi2 * 4;
            #pragma unroll
            for (int r = 0; r < 4; ++r) {
                int m = rbase + r;
                if (m < M) {
                    float v = acc[fm][fn][r] + bv;
                    if (ACT == 0) {
                        Chi[(size_t)m * D + col] = bf16_rne(fmaxf(v, 0.f));
                    } else {
                        Cf[(size_t)m * D + col] = tanhf(v);
                    }
                }
            }
        }
    }
}

// ---------------------------------------------------------------------------
// Final: out[M][64] = softmax(H @ Wlin + blin).
// Wlin in LDS once/block; H via wave-uniform scalar loads; 4 independent
// partial accumulators (chain = fma latency only).
// ---------------------------------------------------------------------------
__global__ void __launch_bounds__(256)
final_softmax(const float* __restrict__ H, const float* __restrict__ Wlin,
              const float* __restrict__ blin, float* __restrict__ out, int M) {
    __shared__ __align__(16) float sW[D * OUT];   // 64 KB
    const int tid = threadIdx.x;
    #pragma unroll
    for (int i = 0; i < 16; ++i) {
        int idx = (i * 256 + tid) * 4;
        *reinterpret_cast<float4*>(&sW[idx]) = *reinterpret_cast<const float4*>(&Wlin[idx]);
    }
    __syncthreads();

    const int wave = tid >> 6, lane = tid & 63;
    const float bl = blin[lane];
    int r0 = blockIdx.x * FS_ROWS + wave * (FS_ROWS / 4);
    int r1 = r0 + FS_ROWS / 4;
    for (int r = r0; r < r1 && r < M; ++r) {
        const float* hrow = H + (size_t)r * D;   // wave-uniform -> scalar loads
        float a0 = 0.f, a1 = 0.f, a2 = 0.f, a3 = 0.f;
        #pragma unroll 8
        for (int k = 0; k < D; k += 4) {
            a0 += hrow[k + 0] * sW[(k + 0) * OUT + lane];
            a1 += hrow[k + 1] * sW[(k + 1) * OUT + lane];
            a2 += hrow[k + 2] * sW[(k + 2) * OUT + lane];
            a3 += hrow[k + 3] * sW[(k + 3) * OUT + lane];
        }
        float acc = (a0 + a1) + (a2 + a3) + bl;
        float mx = acc;
        #pragma unroll
        for (int off = 32; off > 0; off >>= 1) mx = fmaxf(mx, __shfl_xor(mx, off));
        float e = __expf(acc - mx);
        float s = e;
        #pragma unroll
        for (int off = 32; off > 0; off >>= 1) s += __shfl_xor(s, off);
        out[(size_t)r * OUT + lane] = e / s;
    }
}

extern "C" void kernel_launch(void* const* d_in, const int* in_sizes, int n_in,
                              void* d_out, int out_size, void* d_ws, size_t ws_size,
                              hipStream_t stream) {
    const float* x    = (const float*)d_in[0];
    const int*   src0 = (const int*)d_in[1];
    const int*   dst0 = (const int*)d_in[2];
    const int*   src1 = (const int*)d_in[3];
    const int*   dst1 = (const int*)d_in[4];
    const float* Wl0  = (const float*)d_in[5];
    const float* bl0  = (const float*)d_in[6];
    const float* Wr0  = (const float*)d_in[7];
    const float* Wl1  = (const float*)d_in[8];
    const float* bl1  = (const float*)d_in[9];
    const float* Wr1  = (const float*)d_in[10];
    const float* Wlin = (const float*)d_in[11];
    const float* blin = (const float*)d_in[12];

    const int PADX = 200064;  // xhi: all N0 rows (gather sources span N0), 64-row mult
    const int PAD1 = 50048;   // 782*64 (gload_lds reads unmasked -> pad rows)
    const int PAD2 = 10112;   // 158*64

    char* ws = (char*)d_ws;
    size_t off = 0;
    auto alloc = [&](size_t bytes) {
        void* p = ws + off;
        off += (bytes + 255) & ~(size_t)255;
        return p;
    };
    // cnt0 and cnt1 adjacent -> one memset covers both (incl. alignment pad)
    int* cnt0  = (int*)alloc((size_t)N1 * 4);
    int* cnt1  = (int*)alloc((size_t)N2 * 4);
    size_t cnt_span = (size_t)((char*)cnt1 - (char*)cnt0) + (size_t)N2 * 4;
    int* eidx0 = (int*)alloc((size_t)N1 * CAP * 4);
    int* eidx1 = (int*)alloc((size_t)N2 * CAP * 4);
    unsigned short* agg0hi = (unsigned short*)alloc((size_t)PAD1 * D * 2);
    unsigned short* xhi    = (unsigned short*)alloc((size_t)PADX * D * 2);
    unsigned short* h0hi   = (unsigned short*)alloc((size_t)N1 * D * 2);
    unsigned short* agg1hi = (unsigned short*)alloc((size_t)PAD2 * D * 2);
    float* h1f = (float*)alloc((size_t)N2 * D * 4);
    unsigned short* WThi0 = (unsigned short*)alloc((size_t)D * 512 * 2);
    unsigned short* WTlo0 = (unsigned short*)alloc((size_t)D * 512 * 2);
    unsigned short* WThi1 = (unsigned short*)alloc((size_t)D * 512 * 2);
    unsigned short* WTlo1 = (unsigned short*)alloc((size_t)D * 512 * 2);

    hipMemsetAsync(cnt0, 0, cnt_span, stream);

    // cast ALL of x (N0 rows) to bf16: gather sources span [0, N0); gemm A2 uses rows < N1.
    cast_hi<<<(N0 * (D / 4) + 255) / 256, 256, 0, stream>>>(x, xhi, N0 * (D / 4));
    pack_wt2<<<dim3(256, 2), 512, 0, stream>>>(Wl0, Wr0, WThi0, WTlo0,
                                               Wl1, Wr1, WThi1, WTlo1);
    fill_edges2<<<(E0 + E1 + 255) / 256, 256, 0, stream>>>(
        src0, dst0, cnt0, eidx0, src1, dst1, cnt1, eidx1);

    aggregate_h<<<(N1 + 3) / 4, 256, 0, stream>>>(xhi, cnt0, eidx0, agg0hi, N1);
    gemm_split<0><<<dim3((N1 + BM - 1) / BM, 2), 256, 0, stream>>>(
        agg0hi, xhi, WThi0, WTlo0, bl0, h0hi, (float*)nullptr, N1);

    aggregate_h<<<(N2 + 3) / 4, 256, 0, stream>>>(h0hi, cnt1, eidx1, agg1hi, N2);
    gemm_split<1><<<dim3((N2 + BM - 1) / BM, 2), 256, 0, stream>>>(
        agg1hi, h0hi, WThi1, WTlo1, bl1, (unsigned short*)nullptr, h1f, N2);

    final_softmax<<<(N2 + FS_ROWS - 1) / FS_ROWS, 256, 0, stream>>>(
        h1f, Wlin, blin, (float*)d_out, N2);
}

// Round 23
// 272.235 us; speedup vs baseline: 1.4080x; 1.0290x over previous
//
#include <hip/hip_runtime.h>
#include <math.h>

#define N0 200000
#define N1 50000
#define N2 10000
#define E0 750000
#define E1 150000
#define D 256
#define OUT 64
#define CAP 64

#define BM 64
#define BN 128
#define FS_ROWS 32

// prep-kernel block partition (round-23: one launch, fill first so the
// latency-bound atomic blocks overlap under the bandwidth-bound cast stream)
#define FILL_B 3516    // (E0+E1+255)/256
#define PACK_B 512     // 256 n-rows x 2 layers
#define CAST_B 50000   // N0*(D/4)/256

typedef unsigned int uint32;
using short8 = __attribute__((ext_vector_type(8))) short;
using f32x4 = __attribute__((ext_vector_type(4))) float;

// ---- bf16 helpers ----
__device__ __forceinline__ unsigned short bf16_rne(float f) {
    unsigned int u = __float_as_uint(f);
    unsigned int r = (u + 0x7FFFu + ((u >> 16) & 1u)) >> 16;
    return (unsigned short)r;
}
__device__ __forceinline__ float bf16_f32(unsigned short h) {
    return __uint_as_float(((unsigned int)h) << 16);
}

// direct global->LDS copy, 16B per lane. LDS dest = wave-uniform base + lane*16.
__device__ __forceinline__ void gload_lds16(const void* g, void* l) {
    __builtin_amdgcn_global_load_lds(
        (const __attribute__((address_space(1))) unsigned int*)g,
        (__attribute__((address_space(3))) unsigned int*)l, 16, 0, 0);
}

// ---------------------------------------------------------------------------
// Merged prep: edge lists (both layers) + W pack (both layers) + x->bf16 cast
// in ONE launch. Sections are independent (disjoint reads/writes).
// ---------------------------------------------------------------------------
__global__ void prep(const float* __restrict__ x, unsigned short* __restrict__ xhi,
                     const int* __restrict__ src0, const int* __restrict__ dst0,
                     int* __restrict__ cnt0, int* __restrict__ eidx0,
                     const int* __restrict__ src1, const int* __restrict__ dst1,
                     int* __restrict__ cnt1, int* __restrict__ eidx1,
                     const float* __restrict__ Wl0, const float* __restrict__ Wr0,
                     unsigned short* __restrict__ WThi0, unsigned short* __restrict__ WTlo0,
                     const float* __restrict__ Wl1, const float* __restrict__ Wr1,
                     unsigned short* __restrict__ WThi1, unsigned short* __restrict__ WTlo1) {
    int b = blockIdx.x;
    if (b < FILL_B) {
        int e = b * 256 + threadIdx.x;
        if (e < E0) {
            int d = dst0[e];
            int pos = atomicAdd(&cnt0[d], 1);
            if (pos < CAP) eidx0[d * CAP + pos] = src0[e];
        } else if (e < E0 + E1) {
            int e1 = e - E0;
            int d = dst1[e1];
            int pos = atomicAdd(&cnt1[d], 1);
            if (pos < CAP) eidx1[d * CAP + pos] = src1[e1];
        }
    } else if (b < FILL_B + PACK_B) {
        int pb = b - FILL_B;
        int layer = pb >> 8;
        int n = pb & 255;
        const float* Wl = layer ? Wl1 : Wl0;
        const float* Wr = layer ? Wr1 : Wr0;
        unsigned short* WThi = layer ? WThi1 : WThi0;
        unsigned short* WTlo = layer ? WTlo1 : WTlo0;
        #pragma unroll
        for (int kc = threadIdx.x; kc < 512; kc += 256) {
            float v = (kc < 256) ? Wl[(size_t)kc * D + n] : Wr[(size_t)(kc - 256) * D + n];
            unsigned short h = bf16_rne(v);
            WThi[(size_t)n * 512 + kc] = h;
            WTlo[(size_t)n * 512 + kc] = bf16_rne(v - bf16_f32(h));
        }
    } else {
        int i = (b - FILL_B - PACK_B) * 256 + threadIdx.x;   // < N0*64 exactly
        float4 v = *reinterpret_cast<const float4*>(x + (size_t)i * 4);
        ushort4 h;
        h.x = bf16_rne(v.x); h.y = bf16_rne(v.y);
        h.z = bf16_rne(v.z); h.w = bf16_rne(v.w);
        *reinterpret_cast<ushort4*>(xhi + (size_t)i * 4) = h;
    }
}

// ---------------------------------------------------------------------------
// Mean-aggregate neighbor rows from a bf16 plane (512 B/row — at the per-CU
// byte-delivery ceiling, bytes ~= time). fp32 accumulate, bf16 output.
// ---------------------------------------------------------------------------
__global__ void aggregate_h(const unsigned short* __restrict__ srcHi,
                            const int* __restrict__ cnt, const int* __restrict__ eidx,
                            unsigned short* __restrict__ aggHi, int T) {
    int wave = threadIdx.x >> 6;
    int lane = threadIdx.x & 63;
    int t = blockIdx.x * 4 + wave;
    if (t >= T) return;
    int deg = cnt[t];
    int n = deg < CAP ? deg : CAP;
    int vidx = eidx[(size_t)t * CAP + lane];
    float a0 = 0.f, a1 = 0.f, a2 = 0.f, a3 = 0.f;

    for (int j0 = 0; j0 < n; j0 += 4) {
        int   s[4];
        float w[4];
        #pragma unroll
        for (int jj = 0; jj < 4; ++jj) {
            int j = j0 + jj;
            int sv = __shfl(vidx, j);
            bool act = j < n;
            s[jj] = act ? sv : 0;
            w[jj] = act ? 1.f : 0.f;
        }
        ushort4 uh[4];
        #pragma unroll
        for (int jj = 0; jj < 4; ++jj)
            uh[jj] = *reinterpret_cast<const ushort4*>(srcHi + (size_t)s[jj] * D + lane * 4);
        #pragma unroll
        for (int jj = 0; jj < 4; ++jj) {
            a0 += w[jj] * bf16_f32(uh[jj].x);
            a1 += w[jj] * bf16_f32(uh[jj].y);
            a2 += w[jj] * bf16_f32(uh[jj].z);
            a3 += w[jj] * bf16_f32(uh[jj].w);
        }
    }

    float sc = deg > 0 ? 1.0f / (float)deg : 0.0f;
    ushort4 oh;
    oh.x = bf16_rne(a0 * sc); oh.y = bf16_rne(a1 * sc);
    oh.z = bf16_rne(a2 * sc); oh.w = bf16_rne(a3 * sc);
    *reinterpret_cast<ushort4*>(aggHi + (size_t)t * D + lane * 4) = oh;
}

// ---------------------------------------------------------------------------
// MFMA GEMM: C[M][256] = act([A1|A2] @ (Whi+Wlo) + bias), K=512.
// A bf16-only, 2 MFMA terms, 40 KB LDS, 4 blocks/CU (verified r22 win).
// 1-phase schedule (best measured: dbuf r13/r15 and B-global r12 regressed).
// ---------------------------------------------------------------------------
template<int ACT>
__global__ void __launch_bounds__(256, 4)
gemm_split(const unsigned short* __restrict__ A1hi, const unsigned short* __restrict__ A2hi,
           const unsigned short* __restrict__ WThi, const unsigned short* __restrict__ WTlo,
           const float* __restrict__ bias, unsigned short* __restrict__ Chi,
           float* __restrict__ Cf, int M) {
    __shared__ __align__(16) char sAhi[BM * 128];   //  8 KB
    __shared__ __align__(16) char sBhi[BN * 128];   // 16 KB
    __shared__ __align__(16) char sBlo[BN * 128];   // 16 KB

    const int tid = threadIdx.x;
    const int m0 = blockIdx.x * BM;
    const int n0 = blockIdx.y * BN;
    const int wid = tid >> 6, lane = tid & 63;
    const int lr = lane & 15;
    const int hi2 = lane >> 4;

    const int srow = lane >> 3;                    // row within 8-row chunk
    const int scol = ((lane & 7) ^ srow) << 4;     // pre-swizzled source byte col

    f32x4 acc[4][2];
    #pragma unroll
    for (int i = 0; i < 4; ++i)
        #pragma unroll
        for (int j = 0; j < 2; ++j)
            acc[i][j] = (f32x4){0.f, 0.f, 0.f, 0.f};

    for (int k0 = 0; k0 < 512; k0 += 64) {
        if (k0) __syncthreads();   // prior compute done before LDS overwrite
        const char* Ah = (const char*)((k0 < 256) ? A1hi : A2hi);
        const int kc = k0 & 255;
        // A: 8 chunks of 8 rows, 2 per wave (hi plane only)
        #pragma unroll
        for (int i = 0; i < 2; ++i) {
            int ch = wid * 2 + i;
            int row = ch * 8 + srow;
            size_t ga = ((size_t)(m0 + row) * D + kc) * 2 + scol;
            gload_lds16(Ah + ga, sAhi + ch * 1024);
        }
        // B: 16 chunks of 8 rows, 4 per wave, hi+lo planes
        #pragma unroll
        for (int i = 0; i < 4; ++i) {
            int ch = wid * 4 + i;
            int row = ch * 8 + srow;
            size_t gb = ((size_t)(n0 + row) * 512 + k0) * 2 + scol;
            gload_lds16((const char*)WThi + gb, sBhi + ch * 1024);
            gload_lds16((const char*)WTlo + gb, sBlo + ch * 1024);
        }
        __syncthreads();   // vmcnt(0) drained by compiler before barrier

        #pragma unroll
        for (int slab = 0; slab < 2; ++slab) {
            const int z = slab * 64 + hi2 * 16;
            short8 ah[4], bh[2], bl[2];
            #pragma unroll
            for (int f = 0; f < 4; ++f) {
                int ra = f * 16 + lr;
                int oa = ra * 128 + (z ^ ((ra & 7) << 4));
                ah[f] = *reinterpret_cast<const short8*>(sAhi + oa);
            }
            #pragma unroll
            for (int f = 0; f < 2; ++f) {
                int rb = wid * 32 + f * 16 + lr;
                int ob = rb * 128 + (z ^ ((rb & 7) << 4));
                bh[f] = *reinterpret_cast<const short8*>(sBhi + ob);
                bl[f] = *reinterpret_cast<const short8*>(sBlo + ob);
            }
            #pragma unroll
            for (int i = 0; i < 4; ++i)
                #pragma unroll
                for (int j = 0; j < 2; ++j) {
                    acc[i][j] = __builtin_amdgcn_mfma_f32_16x16x32_bf16(ah[i], bh[j], acc[i][j], 0, 0, 0);
                    acc[i][j] = __builtin_amdgcn_mfma_f32_16x16x32_bf16(ah[i], bl[j], acc[i][j], 0, 0, 0);
                }
        }
    }

    // epilogue: D[row][col], col = lane&15, row = (lane>>4)*4 + reg
    #pragma unroll
    for (int fn = 0; fn < 2; ++fn) {
        int col = n0 + wid * 32 + fn * 16 + lr;
        float bv = bias[col];
        #pragma unroll
        for (int fm = 0; fm < 4; ++fm) {
            int rbase = m0 + fm * 16 + hi2 * 4;
            #pragma unroll
            for (int r = 0; r < 4; ++r) {
                int m = rbase + r;
                if (m < M) {
                    float v = acc[fm][fn][r] + bv;
                    if (ACT == 0) {
                        Chi[(size_t)m * D + col] = bf16_rne(fmaxf(v, 0.f));
                    } else {
                        Cf[(size_t)m * D + col] = tanhf(v);
                    }
                }
            }
        }
    }
}

// ---------------------------------------------------------------------------
// Final: out[M][64] = softmax(H @ Wlin + blin).
// Wlin in LDS once/block; H via wave-uniform scalar loads; 4 independent
// partial accumulators (chain = fma latency only).
// ---------------------------------------------------------------------------
__global__ void __launch_bounds__(256)
final_softmax(const float* __restrict__ H, const float* __restrict__ Wlin,
              const float* __restrict__ blin, float* __restrict__ out, int M) {
    __shared__ __align__(16) float sW[D * OUT];   // 64 KB
    const int tid = threadIdx.x;
    #pragma unroll
    for (int i = 0; i < 16; ++i) {
        int idx = (i * 256 + tid) * 4;
        *reinterpret_cast<float4*>(&sW[idx]) = *reinterpret_cast<const float4*>(&Wlin[idx]);
    }
    __syncthreads();

    const int wave = tid >> 6, lane = tid & 63;
    const float bl = blin[lane];
    int r0 = blockIdx.x * FS_ROWS + wave * (FS_ROWS / 4);
    int r1 = r0 + FS_ROWS / 4;
    for (int r = r0; r < r1 && r < M; ++r) {
        const float* hrow = H + (size_t)r * D;   // wave-uniform -> scalar loads
        float a0 = 0.f, a1 = 0.f, a2 = 0.f, a3 = 0.f;
        #pragma unroll 8
        for (int k = 0; k < D; k += 4) {
            a0 += hrow[k + 0] * sW[(k + 0) * OUT + lane];
            a1 += hrow[k + 1] * sW[(k + 1) * OUT + lane];
            a2 += hrow[k + 2] * sW[(k + 2) * OUT + lane];
            a3 += hrow[k + 3] * sW[(k + 3) * OUT + lane];
        }
        float acc = (a0 + a1) + (a2 + a3) + bl;
        float mx = acc;
        #pragma unroll
        for (int off = 32; off > 0; off >>= 1) mx = fmaxf(mx, __shfl_xor(mx, off));
        float e = __expf(acc - mx);
        float s = e;
        #pragma unroll
        for (int off = 32; off > 0; off >>= 1) s += __shfl_xor(s, off);
        out[(size_t)r * OUT + lane] = e / s;
    }
}

extern "C" void kernel_launch(void* const* d_in, const int* in_sizes, int n_in,
                              void* d_out, int out_size, void* d_ws, size_t ws_size,
                              hipStream_t stream) {
    const float* x    = (const float*)d_in[0];
    const int*   src0 = (const int*)d_in[1];
    const int*   dst0 = (const int*)d_in[2];
    const int*   src1 = (const int*)d_in[3];
    const int*   dst1 = (const int*)d_in[4];
    const float* Wl0  = (const float*)d_in[5];
    const float* bl0  = (const float*)d_in[6];
    const float* Wr0  = (const float*)d_in[7];
    const float* Wl1  = (const float*)d_in[8];
    const float* bl1  = (const float*)d_in[9];
    const float* Wr1  = (const float*)d_in[10];
    const float* Wlin = (const float*)d_in[11];
    const float* blin = (const float*)d_in[12];

    const int PADX = 200064;  // xhi: all N0 rows (gather sources span N0), 64-row mult
    const int PAD1 = 50048;   // 782*64 (gload_lds reads unmasked -> pad rows)
    const int PAD2 = 10112;   // 158*64

    char* ws = (char*)d_ws;
    size_t off = 0;
    auto alloc = [&](size_t bytes) {
        void* p = ws + off;
        off += (bytes + 255) & ~(size_t)255;
        return p;
    };
    // cnt0 and cnt1 adjacent -> one memset covers both (incl. alignment pad)
    int* cnt0  = (int*)alloc((size_t)N1 * 4);
    int* cnt1  = (int*)alloc((size_t)N2 * 4);
    size_t cnt_span = (size_t)((char*)cnt1 - (char*)cnt0) + (size_t)N2 * 4;
    int* eidx0 = (int*)alloc((size_t)N1 * CAP * 4);
    int* eidx1 = (int*)alloc((size_t)N2 * CAP * 4);
    unsigned short* agg0hi = (unsigned short*)alloc((size_t)PAD1 * D * 2);
    unsigned short* xhi    = (unsigned short*)alloc((size_t)PADX * D * 2);
    unsigned short* h0hi   = (unsigned short*)alloc((size_t)N1 * D * 2);
    unsigned short* agg1hi = (unsigned short*)alloc((size_t)PAD2 * D * 2);
    float* h1f = (float*)alloc((size_t)N2 * D * 4);
    unsigned short* WThi0 = (unsigned short*)alloc((size_t)D * 512 * 2);
    unsigned short* WTlo0 = (unsigned short*)alloc((size_t)D * 512 * 2);
    unsigned short* WThi1 = (unsigned short*)alloc((size_t)D * 512 * 2);
    unsigned short* WTlo1 = (unsigned short*)alloc((size_t)D * 512 * 2);

    hipMemsetAsync(cnt0, 0, cnt_span, stream);

    prep<<<FILL_B + PACK_B + CAST_B, 256, 0, stream>>>(
        x, xhi, src0, dst0, cnt0, eidx0, src1, dst1, cnt1, eidx1,
        Wl0, Wr0, WThi0, WTlo0, Wl1, Wr1, WThi1, WTlo1);

    aggregate_h<<<(N1 + 3) / 4, 256, 0, stream>>>(xhi, cnt0, eidx0, agg0hi, N1);
    gemm_split<0><<<dim3((N1 + BM - 1) / BM, 2), 256, 0, stream>>>(
        agg0hi, xhi, WThi0, WTlo0, bl0, h0hi, (float*)nullptr, N1);

    aggregate_h<<<(N2 + 3) / 4, 256, 0, stream>>>(h0hi, cnt1, eidx1, agg1hi, N2);
    gemm_split<1><<<dim3((N2 + BM - 1) / BM, 2), 256, 0, stream>>>(
        agg1hi, h0hi, WThi1, WTlo1, bl1, (unsigned short*)nullptr, h1f, N2);

    final_softmax<<<(N2 + FS_ROWS - 1) / FS_ROWS, 256, 0, stream>>>(
        h1f, Wlin, blin, (float*)d_out, N2);
}

// Round 24
// 263.794 us; speedup vs baseline: 1.4531x; 1.0320x over previous
//
#include <hip/hip_runtime.h>
#include <math.h>

#define N0 200000
#define N1 50000
#define N2 10000
#define E0 750000
#define E1 150000
#define D 256
#define OUT 64
#define CAP 64

#define BM 64
#define BN 128
#define FS_ROWS 32

// prep-kernel partition (round-24): cast/pack blocks carry the bandwidth;
// fill blocks (x4-unrolled atomics) interleaved 1-in-58 so their latency
// hides under the cast stream. r23 post-mortem: fill-first ordering
// serialized the phases (130 us = 80 fill + 48 cast).
#define CAST_B 50000            // N0*(D/4)/256 exactly
#define PACK_B 512              // 256 n-rows x 2 layers
#define FILL4_B 879             // ceil((E0+E1)/1024)
#define ISTRIDE 58              // fill block every 58th
#define GRID_B (CAST_B + PACK_B + FILL4_B)

typedef unsigned int uint32;
using short8 = __attribute__((ext_vector_type(8))) short;
using f32x4 = __attribute__((ext_vector_type(4))) float;

// ---- bf16 helpers ----
__device__ __forceinline__ unsigned short bf16_rne(float f) {
    unsigned int u = __float_as_uint(f);
    unsigned int r = (u + 0x7FFFu + ((u >> 16) & 1u)) >> 16;
    return (unsigned short)r;
}
__device__ __forceinline__ float bf16_f32(unsigned short h) {
    return __uint_as_float(((unsigned int)h) << 16);
}

// direct global->LDS copy, 16B per lane. LDS dest = wave-uniform base + lane*16.
__device__ __forceinline__ void gload_lds16(const void* g, void* l) {
    __builtin_amdgcn_global_load_lds(
        (const __attribute__((address_space(1))) unsigned int*)g,
        (__attribute__((address_space(3))) unsigned int*)l, 16, 0, 0);
}

// ---------------------------------------------------------------------------
// Merged prep: x->bf16 cast + W pack + edge-list build, one launch.
// Fill blocks interleaved among cast blocks; 4 edges/thread for 4x atomic MLP.
// ---------------------------------------------------------------------------
__global__ void prep(const float* __restrict__ x, unsigned short* __restrict__ xhi,
                     const int* __restrict__ src0, const int* __restrict__ dst0,
                     int* __restrict__ cnt0, int* __restrict__ eidx0,
                     const int* __restrict__ src1, const int* __restrict__ dst1,
                     int* __restrict__ cnt1, int* __restrict__ eidx1,
                     const float* __restrict__ Wl0, const float* __restrict__ Wr0,
                     unsigned short* __restrict__ WThi0, unsigned short* __restrict__ WTlo0,
                     const float* __restrict__ Wl1, const float* __restrict__ Wr1,
                     unsigned short* __restrict__ WThi1, unsigned short* __restrict__ WTlo1) {
    int b = blockIdx.x;
    int k = b / ISTRIDE;
    bool isfill = ((b % ISTRIDE) == ISTRIDE - 1) && (k < FILL4_B);
    if (isfill) {
        int e0 = k * 1024 + threadIdx.x * 4;       // aligned group of 4 edges
        if (e0 < E0) {                              // fully in layer 0 (E0%4==0)
            int4 dv = *reinterpret_cast<const int4*>(dst0 + e0);
            int4 sv = *reinterpret_cast<const int4*>(src0 + e0);
            int p0 = atomicAdd(&cnt0[dv.x], 1);
            int p1 = atomicAdd(&cnt0[dv.y], 1);
            int p2 = atomicAdd(&cnt0[dv.z], 1);
            int p3 = atomicAdd(&cnt0[dv.w], 1);
            if (p0 < CAP) eidx0[dv.x * CAP + p0] = sv.x;
            if (p1 < CAP) eidx0[dv.y * CAP + p1] = sv.y;
            if (p2 < CAP) eidx0[dv.z * CAP + p2] = sv.z;
            if (p3 < CAP) eidx0[dv.w * CAP + p3] = sv.w;
        } else if (e0 < E0 + E1) {                  // fully in layer 1 ((E0+E1)%4==0)
            int e1 = e0 - E0;
            int4 dv = *reinterpret_cast<const int4*>(dst1 + e1);
            int4 sv = *reinterpret_cast<const int4*>(src1 + e1);
            int p0 = atomicAdd(&cnt1[dv.x], 1);
            int p1 = atomicAdd(&cnt1[dv.y], 1);
            int p2 = atomicAdd(&cnt1[dv.z], 1);
            int p3 = atomicAdd(&cnt1[dv.w], 1);
            if (p0 < CAP) eidx1[dv.x * CAP + p0] = sv.x;
            if (p1 < CAP) eidx1[dv.y * CAP + p1] = sv.y;
            if (p2 < CAP) eidx1[dv.z * CAP + p2] = sv.z;
            if (p3 < CAP) eidx1[dv.w * CAP + p3] = sv.w;
        }                                           // else: OOB tail lanes, skip
    } else {
        int nf = (b + 1) / ISTRIDE;
        if (nf > FILL4_B) nf = FILL4_B;
        int r = b - nf;                             // rank among non-fill blocks
        if (r < CAST_B) {
            int i = r * 256 + threadIdx.x;          // < N0*64 exactly
            float4 v = *reinterpret_cast<const float4*>(x + (size_t)i * 4);
            ushort4 h;
            h.x = bf16_rne(v.x); h.y = bf16_rne(v.y);
            h.z = bf16_rne(v.z); h.w = bf16_rne(v.w);
            *reinterpret_cast<ushort4*>(xhi + (size_t)i * 4) = h;
        } else {
            int pb = r - CAST_B;
            int layer = pb >> 8;
            int n = pb & 255;
            const float* Wl = layer ? Wl1 : Wl0;
            const float* Wr = layer ? Wr1 : Wr0;
            unsigned short* WThi = layer ? WThi1 : WThi0;
            unsigned short* WTlo = layer ? WTlo1 : WTlo0;
            #pragma unroll
            for (int kc = threadIdx.x; kc < 512; kc += 256) {
                float v = (kc < 256) ? Wl[(size_t)kc * D + n] : Wr[(size_t)(kc - 256) * D + n];
                unsigned short h = bf16_rne(v);
                WThi[(size_t)n * 512 + kc] = h;
                WTlo[(size_t)n * 512 + kc] = bf16_rne(v - bf16_f32(h));
            }
        }
    }
}

// ---------------------------------------------------------------------------
// Mean-aggregate neighbor rows from a bf16 plane (512 B/row — at the per-CU
// byte-delivery ceiling, bytes ~= time). fp32 accumulate, bf16 output.
// ---------------------------------------------------------------------------
__global__ void aggregate_h(const unsigned short* __restrict__ srcHi,
                            const int* __restrict__ cnt, const int* __restrict__ eidx,
                            unsigned short* __restrict__ aggHi, int T) {
    int wave = threadIdx.x >> 6;
    int lane = threadIdx.x & 63;
    int t = blockIdx.x * 4 + wave;
    if (t >= T) return;
    int deg = cnt[t];
    int n = deg < CAP ? deg : CAP;
    int vidx = eidx[(size_t)t * CAP + lane];
    float a0 = 0.f, a1 = 0.f, a2 = 0.f, a3 = 0.f;

    for (int j0 = 0; j0 < n; j0 += 4) {
        int   s[4];
        float w[4];
        #pragma unroll
        for (int jj = 0; jj < 4; ++jj) {
            int j = j0 + jj;
            int sv = __shfl(vidx, j);
            bool act = j < n;
            s[jj] = act ? sv : 0;
            w[jj] = act ? 1.f : 0.f;
        }
        ushort4 uh[4];
        #pragma unroll
        for (int jj = 0; jj < 4; ++jj)
            uh[jj] = *reinterpret_cast<const ushort4*>(srcHi + (size_t)s[jj] * D + lane * 4);
        #pragma unroll
        for (int jj = 0; jj < 4; ++jj) {
            a0 += w[jj] * bf16_f32(uh[jj].x);
            a1 += w[jj] * bf16_f32(uh[jj].y);
            a2 += w[jj] * bf16_f32(uh[jj].z);
            a3 += w[jj] * bf16_f32(uh[jj].w);
        }
    }

    float sc = deg > 0 ? 1.0f / (float)deg : 0.0f;
    ushort4 oh;
    oh.x = bf16_rne(a0 * sc); oh.y = bf16_rne(a1 * sc);
    oh.z = bf16_rne(a2 * sc); oh.w = bf16_rne(a3 * sc);
    *reinterpret_cast<ushort4*>(aggHi + (size_t)t * D + lane * 4) = oh;
}

// ---------------------------------------------------------------------------
// MFMA GEMM: C[M][256] = act([A1|A2] @ (Whi+Wlo) + bias), K=512.
// A bf16-only, 2 MFMA terms, 40 KB LDS, 4 blocks/CU (verified r22 win).
// 1-phase schedule (best measured: dbuf r13/r15 and B-global r12 regressed).
// ---------------------------------------------------------------------------
template<int ACT>
__global__ void __launch_bounds__(256, 4)
gemm_split(const unsigned short* __restrict__ A1hi, const unsigned short* __restrict__ A2hi,
           const unsigned short* __restrict__ WThi, const unsigned short* __restrict__ WTlo,
           const float* __restrict__ bias, unsigned short* __restrict__ Chi,
           float* __restrict__ Cf, int M) {
    __shared__ __align__(16) char sAhi[BM * 128];   //  8 KB
    __shared__ __align__(16) char sBhi[BN * 128];   // 16 KB
    __shared__ __align__(16) char sBlo[BN * 128];   // 16 KB

    const int tid = threadIdx.x;
    const int m0 = blockIdx.x * BM;
    const int n0 = blockIdx.y * BN;
    const int wid = tid >> 6, lane = tid & 63;
    const int lr = lane & 15;
    const int hi2 = lane >> 4;

    const int srow = lane >> 3;                    // row within 8-row chunk
    const int scol = ((lane & 7) ^ srow) << 4;     // pre-swizzled source byte col

    f32x4 acc[4][2];
    #pragma unroll
    for (int i = 0; i < 4; ++i)
        #pragma unroll
        for (int j = 0; j < 2; ++j)
            acc[i][j] = (f32x4){0.f, 0.f, 0.f, 0.f};

    for (int k0 = 0; k0 < 512; k0 += 64) {
        if (k0) __syncthreads();   // prior compute done before LDS overwrite
        const char* Ah = (const char*)((k0 < 256) ? A1hi : A2hi);
        const int kc = k0 & 255;
        // A: 8 chunks of 8 rows, 2 per wave (hi plane only)
        #pragma unroll
        for (int i = 0; i < 2; ++i) {
            int ch = wid * 2 + i;
            int row = ch * 8 + srow;
            size_t ga = ((size_t)(m0 + row) * D + kc) * 2 + scol;
            gload_lds16(Ah + ga, sAhi + ch * 1024);
        }
        // B: 16 chunks of 8 rows, 4 per wave, hi+lo planes
        #pragma unroll
        for (int i = 0; i < 4; ++i) {
            int ch = wid * 4 + i;
            int row = ch * 8 + srow;
            size_t gb = ((size_t)(n0 + row) * 512 + k0) * 2 + scol;
            gload_lds16((const char*)WThi + gb, sBhi + ch * 1024);
            gload_lds16((const char*)WTlo + gb, sBlo + ch * 1024);
        }
        __syncthreads();   // vmcnt(0) drained by compiler before barrier

        #pragma unroll
        for (int slab = 0; slab < 2; ++slab) {
            const int z = slab * 64 + hi2 * 16;
            short8 ah[4], bh[2], bl[2];
            #pragma unroll
            for (int f = 0; f < 4; ++f) {
                int ra = f * 16 + lr;
                int oa = ra * 128 + (z ^ ((ra & 7) << 4));
                ah[f] = *reinterpret_cast<const short8*>(sAhi + oa);
            }
            #pragma unroll
            for (int f = 0; f < 2; ++f) {
                int rb = wid * 32 + f * 16 + lr;
                int ob = rb * 128 + (z ^ ((rb & 7) << 4));
                bh[f] = *reinterpret_cast<const short8*>(sBhi + ob);
                bl[f] = *reinterpret_cast<const short8*>(sBlo + ob);
            }
            #pragma unroll
            for (int i = 0; i < 4; ++i)
                #pragma unroll
                for (int j = 0; j < 2; ++j) {
                    acc[i][j] = __builtin_amdgcn_mfma_f32_16x16x32_bf16(ah[i], bh[j], acc[i][j], 0, 0, 0);
                    acc[i][j] = __builtin_amdgcn_mfma_f32_16x16x32_bf16(ah[i], bl[j], acc[i][j], 0, 0, 0);
                }
        }
    }

    // epilogue: D[row][col], col = lane&15, row = (lane>>4)*4 + reg
    #pragma unroll
    for (int fn = 0; fn < 2; ++fn) {
        int col = n0 + wid * 32 + fn * 16 + lr;
        float bv = bias[col];
        #pragma unroll
        for (int fm = 0; fm < 4; ++fm) {
            int rbase = m0 + fm * 16 + hi2 * 4;
            #pragma unroll
            for (int r = 0; r < 4; ++r) {
                int m = rbase + r;
                if (m < M) {
                    float v = acc[fm][fn][r] + bv;
                    if (ACT == 0) {
                        Chi[(size_t)m * D + col] = bf16_rne(fmaxf(v, 0.f));
                    } else {
                        Cf[(size_t)m * D + col] = tanhf(v);
                    }
                }
            }
        }
    }
}

// ---------------------------------------------------------------------------
// Final: out[M][64] = softmax(H @ Wlin + blin).
// Wlin in LDS once/block; H via wave-uniform scalar loads; 4 independent
// partial accumulators (chain = fma latency only).
// ---------------------------------------------------------------------------
__global__ void __launch_bounds__(256)
final_softmax(const float* __restrict__ H, const float* __restrict__ Wlin,
              const float* __restrict__ blin, float* __restrict__ out, int M) {
    __shared__ __align__(16) float sW[D * OUT];   // 64 KB
    const int tid = threadIdx.x;
    #pragma unroll
    for (int i = 0; i < 16; ++i) {
        int idx = (i * 256 + tid) * 4;
        *reinterpret_cast<float4*>(&sW[idx]) = *reinterpret_cast<const float4*>(&Wlin[idx]);
    }
    __syncthreads();

    const int wave = tid >> 6, lane = tid & 63;
    const float bl = blin[lane];
    int r0 = blockIdx.x * FS_ROWS + wave * (FS_ROWS / 4);
    int r1 = r0 + FS_ROWS / 4;
    for (int r = r0; r < r1 && r < M; ++r) {
        const float* hrow = H + (size_t)r * D;   // wave-uniform -> scalar loads
        float a0 = 0.f, a1 = 0.f, a2 = 0.f, a3 = 0.f;
        #pragma unroll 8
        for (int k = 0; k < D; k += 4) {
            a0 += hrow[k + 0] * sW[(k + 0) * OUT + lane];
            a1 += hrow[k + 1] * sW[(k + 1) * OUT + lane];
            a2 += hrow[k + 2] * sW[(k + 2) * OUT + lane];
            a3 += hrow[k + 3] * sW[(k + 3) * OUT + lane];
        }
        float acc = (a0 + a1) + (a2 + a3) + bl;
        float mx = acc;
        #pragma unroll
        for (int off = 32; off > 0; off >>= 1) mx = fmaxf(mx, __shfl_xor(mx, off));
        float e = __expf(acc - mx);
        float s = e;
        #pragma unroll
        for (int off = 32; off > 0; off >>= 1) s += __shfl_xor(s, off);
        out[(size_t)r * OUT + lane] = e / s;
    }
}

extern "C" void kernel_launch(void* const* d_in, const int* in_sizes, int n_in,
                              void* d_out, int out_size, void* d_ws, size_t ws_size,
                              hipStream_t stream) {
    const float* x    = (const float*)d_in[0];
    const int*   src0 = (const int*)d_in[1];
    const int*   dst0 = (const int*)d_in[2];
    const int*   src1 = (const int*)d_in[3];
    const int*   dst1 = (const int*)d_in[4];
    const float* Wl0  = (const float*)d_in[5];
    const float* bl0  = (const float*)d_in[6];
    const float* Wr0  = (const float*)d_in[7];
    const float* Wl1  = (const float*)d_in[8];
    const float* bl1  = (const float*)d_in[9];
    const float* Wr1  = (const float*)d_in[10];
    const float* Wlin = (const float*)d_in[11];
    const float* blin = (const float*)d_in[12];

    const int PADX = 200064;  // xhi: all N0 rows (gather sources span N0), 64-row mult
    const int PAD1 = 50048;   // 782*64 (gload_lds reads unmasked -> pad rows)
    const int PAD2 = 10112;   // 158*64

    char* ws = (char*)d_ws;
    size_t off = 0;
    auto alloc = [&](size_t bytes) {
        void* p = ws + off;
        off += (bytes + 255) & ~(size_t)255;
        return p;
    };
    // cnt0 and cnt1 adjacent -> one memset covers both (incl. alignment pad)
    int* cnt0  = (int*)alloc((size_t)N1 * 4);
    int* cnt1  = (int*)alloc((size_t)N2 * 4);
    size_t cnt_span = (size_t)((char*)cnt1 - (char*)cnt0) + (size_t)N2 * 4;
    int* eidx0 = (int*)alloc((size_t)N1 * CAP * 4);
    int* eidx1 = (int*)alloc((size_t)N2 * CAP * 4);
    unsigned short* agg0hi = (unsigned short*)alloc((size_t)PAD1 * D * 2);
    unsigned short* xhi    = (unsigned short*)alloc((size_t)PADX * D * 2);
    unsigned short* h0hi   = (unsigned short*)alloc((size_t)N1 * D * 2);
    unsigned short* agg1hi = (unsigned short*)alloc((size_t)PAD2 * D * 2);
    float* h1f = (float*)alloc((size_t)N2 * D * 4);
    unsigned short* WThi0 = (unsigned short*)alloc((size_t)D * 512 * 2);
    unsigned short* WTlo0 = (unsigned short*)alloc((size_t)D * 512 * 2);
    unsigned short* WThi1 = (unsigned short*)alloc((size_t)D * 512 * 2);
    unsigned short* WTlo1 = (unsigned short*)alloc((size_t)D * 512 * 2);

    hipMemsetAsync(cnt0, 0, cnt_span, stream);

    prep<<<GRID_B, 256, 0, stream>>>(
        x, xhi, src0, dst0, cnt0, eidx0, src1, dst1, cnt1, eidx1,
        Wl0, Wr0, WThi0, WTlo0, Wl1, Wr1, WThi1, WTlo1);

    aggregate_h<<<(N1 + 3) / 4, 256, 0, stream>>>(xhi, cnt0, eidx0, agg0hi, N1);
    gemm_split<0><<<dim3((N1 + BM - 1) / BM, 2), 256, 0, stream>>>(
        agg0hi, xhi, WThi0, WTlo0, bl0, h0hi, (float*)nullptr, N1);

    aggregate_h<<<(N2 + 3) / 4, 256, 0, stream>>>(h0hi, cnt1, eidx1, agg1hi, N2);
    gemm_split<1><<<dim3((N2 + BM - 1) / BM, 2), 256, 0, stream>>>(
        agg1hi, h0hi, WThi1, WTlo1, bl1, (unsigned short*)nullptr, h1f, N2);

    final_softmax<<<(N2 + FS_ROWS - 1) / FS_ROWS, 256, 0, stream>>>(
        h1f, Wlin, blin, (float*)d_out, N2);
}

// Round 25
// 249.661 us; speedup vs baseline: 1.5354x; 1.0566x over previous
//
#include <hip/hip_runtime.h>
#include <math.h>

#define N0 200000
#define N1 50000
#define N2 10000
#define E0 750000
#define E1 150000
#define D 256
#define OUT 64
#define CAP 64

#define BM 64
#define BN 128
#define FS_ROWS 32

// prep partition (round-25): 50000 cast blocks EACH carry 18 edges as
// instruction-level shadow work (50000*18 = E0+E1 exactly); 512 pack blocks.
// r24 post-mortem: block-level interleave failed (fill blocks straggle on
// atomic latency while the machine idles); embedding the atomic chains in
// the cast blocks' load-latency shadow uses 50000 blocks' latency slots.
#define CAST_B 50000            // N0*(D/4)/256 exactly
#define PACK_B 512              // 256 n-rows x 2 layers
#define EPB 18                  // edges per cast block

typedef unsigned int uint32;
using short8 = __attribute__((ext_vector_type(8))) short;
using f32x4 = __attribute__((ext_vector_type(4))) float;

// ---- bf16 helpers ----
__device__ __forceinline__ unsigned short bf16_rne(float f) {
    unsigned int u = __float_as_uint(f);
    unsigned int r = (u + 0x7FFFu + ((u >> 16) & 1u)) >> 16;
    return (unsigned short)r;
}
__device__ __forceinline__ float bf16_f32(unsigned short h) {
    return __uint_as_float(((unsigned int)h) << 16);
}

// direct global->LDS copy, 16B per lane. LDS dest = wave-uniform base + lane*16.
__device__ __forceinline__ void gload_lds16(const void* g, void* l) {
    __builtin_amdgcn_global_load_lds(
        (const __attribute__((address_space(1))) unsigned int*)g,
        (__attribute__((address_space(3))) unsigned int*)l, 16, 0, 0);
}

// ---------------------------------------------------------------------------
// Merged prep: x->bf16 cast with 18 edges/block as latency-shadow work,
// plus W pack. One launch.
// ---------------------------------------------------------------------------
__global__ void prep(const float* __restrict__ x, unsigned short* __restrict__ xhi,
                     const int* __restrict__ src0, const int* __restrict__ dst0,
                     int* __restrict__ cnt0, int* __restrict__ eidx0,
                     const int* __restrict__ src1, const int* __restrict__ dst1,
                     int* __restrict__ cnt1, int* __restrict__ eidx1,
                     const float* __restrict__ Wl0, const float* __restrict__ Wr0,
                     unsigned short* __restrict__ WThi0, unsigned short* __restrict__ WTlo0,
                     const float* __restrict__ Wl1, const float* __restrict__ Wr1,
                     unsigned short* __restrict__ WThi1, unsigned short* __restrict__ WTlo1) {
    int b = blockIdx.x;
    if (b < CAST_B) {
        // issue the bandwidth-carrying cast load first
        int i = b * 256 + threadIdx.x;              // < N0*64 exactly
        float4 v = *reinterpret_cast<const float4*>(x + (size_t)i * 4);
        // edge shadow work: lanes 0..17 handle one edge each, their atomic
        // round-trips hide under the cast load latency above
        if (threadIdx.x < EPB) {
            int e = b * EPB + threadIdx.x;          // < E0+E1 exactly
            if (e < E0) {
                int d = dst0[e];
                int pos = atomicAdd(&cnt0[d], 1);
                if (pos < CAP) eidx0[d * CAP + pos] = src0[e];
            } else {
                int e1 = e - E0;
                int d = dst1[e1];
                int pos = atomicAdd(&cnt1[d], 1);
                if (pos < CAP) eidx1[d * CAP + pos] = src1[e1];
            }
        }
        ushort4 h;
        h.x = bf16_rne(v.x); h.y = bf16_rne(v.y);
        h.z = bf16_rne(v.z); h.w = bf16_rne(v.w);
        *reinterpret_cast<ushort4*>(xhi + (size_t)i * 4) = h;
    } else {
        int pb = b - CAST_B;
        int layer = pb >> 8;
        int n = pb & 255;
        const float* Wl = layer ? Wl1 : Wl0;
        const float* Wr = layer ? Wr1 : Wr0;
        unsigned short* WThi = layer ? WThi1 : WThi0;
        unsigned short* WTlo = layer ? WTlo1 : WTlo0;
        #pragma unroll
        for (int kc = threadIdx.x; kc < 512; kc += 256) {
            float v = (kc < 256) ? Wl[(size_t)kc * D + n] : Wr[(size_t)(kc - 256) * D + n];
            unsigned short h = bf16_rne(v);
            WThi[(size_t)n * 512 + kc] = h;
            WTlo[(size_t)n * 512 + kc] = bf16_rne(v - bf16_f32(h));
        }
    }
}

// ---------------------------------------------------------------------------
// Mean-aggregate neighbor rows from a bf16 plane (512 B/row — at the per-CU
// byte-delivery ceiling, bytes ~= time). fp32 accumulate, bf16 output.
// ---------------------------------------------------------------------------
__global__ void aggregate_h(const unsigned short* __restrict__ srcHi,
                            const int* __restrict__ cnt, const int* __restrict__ eidx,
                            unsigned short* __restrict__ aggHi, int T) {
    int wave = threadIdx.x >> 6;
    int lane = threadIdx.x & 63;
    int t = blockIdx.x * 4 + wave;
    if (t >= T) return;
    int deg = cnt[t];
    int n = deg < CAP ? deg : CAP;
    int vidx = eidx[(size_t)t * CAP + lane];
    float a0 = 0.f, a1 = 0.f, a2 = 0.f, a3 = 0.f;

    for (int j0 = 0; j0 < n; j0 += 4) {
        int   s[4];
        float w[4];
        #pragma unroll
        for (int jj = 0; jj < 4; ++jj) {
            int j = j0 + jj;
            int sv = __shfl(vidx, j);
            bool act = j < n;
            s[jj] = act ? sv : 0;
            w[jj] = act ? 1.f : 0.f;
        }
        ushort4 uh[4];
        #pragma unroll
        for (int jj = 0; jj < 4; ++jj)
            uh[jj] = *reinterpret_cast<const ushort4*>(srcHi + (size_t)s[jj] * D + lane * 4);
        #pragma unroll
        for (int jj = 0; jj < 4; ++jj) {
            a0 += w[jj] * bf16_f32(uh[jj].x);
            a1 += w[jj] * bf16_f32(uh[jj].y);
            a2 += w[jj] * bf16_f32(uh[jj].z);
            a3 += w[jj] * bf16_f32(uh[jj].w);
        }
    }

    float sc = deg > 0 ? 1.0f / (float)deg : 0.0f;
    ushort4 oh;
    oh.x = bf16_rne(a0 * sc); oh.y = bf16_rne(a1 * sc);
    oh.z = bf16_rne(a2 * sc); oh.w = bf16_rne(a3 * sc);
    *reinterpret_cast<ushort4*>(aggHi + (size_t)t * D + lane * 4) = oh;
}

// ---------------------------------------------------------------------------
// MFMA GEMM: C[M][256] = act([A1|A2] @ (Whi+Wlo) + bias), K=512.
// A bf16-only, 2 MFMA terms, 40 KB LDS, 4 blocks/CU (verified r22 win).
// 1-phase schedule (best measured: dbuf r13/r15 and B-global r12 regressed).
// ---------------------------------------------------------------------------
template<int ACT>
__global__ void __launch_bounds__(256, 4)
gemm_split(const unsigned short* __restrict__ A1hi, const unsigned short* __restrict__ A2hi,
           const unsigned short* __restrict__ WThi, const unsigned short* __restrict__ WTlo,
           const float* __restrict__ bias, unsigned short* __restrict__ Chi,
           float* __restrict__ Cf, int M) {
    __shared__ __align__(16) char sAhi[BM * 128];   //  8 KB
    __shared__ __align__(16) char sBhi[BN * 128];   // 16 KB
    __shared__ __align__(16) char sBlo[BN * 128];   // 16 KB

    const int tid = threadIdx.x;
    const int m0 = blockIdx.x * BM;
    const int n0 = blockIdx.y * BN;
    const int wid = tid >> 6, lane = tid & 63;
    const int lr = lane & 15;
    const int hi2 = lane >> 4;

    const int srow = lane >> 3;                    // row within 8-row chunk
    const int scol = ((lane & 7) ^ srow) << 4;     // pre-swizzled source byte col

    f32x4 acc[4][2];
    #pragma unroll
    for (int i = 0; i < 4; ++i)
        #pragma unroll
        for (int j = 0; j < 2; ++j)
            acc[i][j] = (f32x4){0.f, 0.f, 0.f, 0.f};

    for (int k0 = 0; k0 < 512; k0 += 64) {
        if (k0) __syncthreads();   // prior compute done before LDS overwrite
        const char* Ah = (const char*)((k0 < 256) ? A1hi : A2hi);
        const int kc = k0 & 255;
        // A: 8 chunks of 8 rows, 2 per wave (hi plane only)
        #pragma unroll
        for (int i = 0; i < 2; ++i) {
            int ch = wid * 2 + i;
            int row = ch * 8 + srow;
            size_t ga = ((size_t)(m0 + row) * D + kc) * 2 + scol;
            gload_lds16(Ah + ga, sAhi + ch * 1024);
        }
        // B: 16 chunks of 8 rows, 4 per wave, hi+lo planes
        #pragma unroll
        for (int i = 0; i < 4; ++i) {
            int ch = wid * 4 + i;
            int row = ch * 8 + srow;
            size_t gb = ((size_t)(n0 + row) * 512 + k0) * 2 + scol;
            gload_lds16((const char*)WThi + gb, sBhi + ch * 1024);
            gload_lds16((const char*)WTlo + gb, sBlo + ch * 1024);
        }
        __syncthreads();   // vmcnt(0) drained by compiler before barrier

        #pragma unroll
        for (int slab = 0; slab < 2; ++slab) {
            const int z = slab * 64 + hi2 * 16;
            short8 ah[4], bh[2], bl[2];
            #pragma unroll
            for (int f = 0; f < 4; ++f) {
                int ra = f * 16 + lr;
                int oa = ra * 128 + (z ^ ((ra & 7) << 4));
                ah[f] = *reinterpret_cast<const short8*>(sAhi + oa);
            }
            #pragma unroll
            for (int f = 0; f < 2; ++f) {
                int rb = wid * 32 + f * 16 + lr;
                int ob = rb * 128 + (z ^ ((rb & 7) << 4));
                bh[f] = *reinterpret_cast<const short8*>(sBhi + ob);
                bl[f] = *reinterpret_cast<const short8*>(sBlo + ob);
            }
            #pragma unroll
            for (int i = 0; i < 4; ++i)
                #pragma unroll
                for (int j = 0; j < 2; ++j) {
                    acc[i][j] = __builtin_amdgcn_mfma_f32_16x16x32_bf16(ah[i], bh[j], acc[i][j], 0, 0, 0);
                    acc[i][j] = __builtin_amdgcn_mfma_f32_16x16x32_bf16(ah[i], bl[j], acc[i][j], 0, 0, 0);
                }
        }
    }

    // epilogue: D[row][col], col = lane&15, row = (lane>>4)*4 + reg
    #pragma unroll
    for (int fn = 0; fn < 2; ++fn) {
        int col = n0 + wid * 32 + fn * 16 + lr;
        float bv = bias[col];
        #pragma unroll
        for (int fm = 0; fm < 4; ++fm) {
            int rbase = m0 + fm * 16 + hi2 * 4;
            #pragma unroll
            for (int r = 0; r < 4; ++r) {
                int m = rbase + r;
                if (m < M) {
                    float v = acc[fm][fn][r] + bv;
                    if (ACT == 0) {
                        Chi[(size_t)m * D + col] = bf16_rne(fmaxf(v, 0.f));
                    } else {
                        Cf[(size_t)m * D + col] = tanhf(v);
                    }
                }
            }
        }
    }
}

// ---------------------------------------------------------------------------
// Final: out[M][64] = softmax(H @ Wlin + blin).
// Wlin in LDS once/block; H via wave-uniform scalar loads; 4 independent
// partial accumulators (chain = fma latency only).
// ---------------------------------------------------------------------------
__global__ void __launch_bounds__(256)
final_softmax(const float* __restrict__ H, const float* __restrict__ Wlin,
              const float* __restrict__ blin, float* __restrict__ out, int M) {
    __shared__ __align__(16) float sW[D * OUT];   // 64 KB
    const int tid = threadIdx.x;
    #pragma unroll
    for (int i = 0; i < 16; ++i) {
        int idx = (i * 256 + tid) * 4;
        *reinterpret_cast<float4*>(&sW[idx]) = *reinterpret_cast<const float4*>(&Wlin[idx]);
    }
    __syncthreads();

    const int wave = tid >> 6, lane = tid & 63;
    const float bl = blin[lane];
    int r0 = blockIdx.x * FS_ROWS + wave * (FS_ROWS / 4);
    int r1 = r0 + FS_ROWS / 4;
    for (int r = r0; r < r1 && r < M; ++r) {
        const float* hrow = H + (size_t)r * D;   // wave-uniform -> scalar loads
        float a0 = 0.f, a1 = 0.f, a2 = 0.f, a3 = 0.f;
        #pragma unroll 8
        for (int k = 0; k < D; k += 4) {
            a0 += hrow[k + 0] * sW[(k + 0) * OUT + lane];
            a1 += hrow[k + 1] * sW[(k + 1) * OUT + lane];
            a2 += hrow[k + 2] * sW[(k + 2) * OUT + lane];
            a3 += hrow[k + 3] * sW[(k + 3) * OUT + lane];
        }
        float acc = (a0 + a1) + (a2 + a3) + bl;
        float mx = acc;
        #pragma unroll
        for (int off = 32; off > 0; off >>= 1) mx = fmaxf(mx, __shfl_xor(mx, off));
        float e = __expf(acc - mx);
        float s = e;
        #pragma unroll
        for (int off = 32; off > 0; off >>= 1) s += __shfl_xor(s, off);
        out[(size_t)r * OUT + lane] = e / s;
    }
}

extern "C" void kernel_launch(void* const* d_in, const int* in_sizes, int n_in,
                              void* d_out, int out_size, void* d_ws, size_t ws_size,
                              hipStream_t stream) {
    const float* x    = (const float*)d_in[0];
    const int*   src0 = (const int*)d_in[1];
    const int*   dst0 = (const int*)d_in[2];
    const int*   src1 = (const int*)d_in[3];
    const int*   dst1 = (const int*)d_in[4];
    const float* Wl0  = (const float*)d_in[5];
    const float* bl0  = (const float*)d_in[6];
    const float* Wr0  = (const float*)d_in[7];
    const float* Wl1  = (const float*)d_in[8];
    const float* bl1  = (const float*)d_in[9];
    const float* Wr1  = (const float*)d_in[10];
    const float* Wlin = (const float*)d_in[11];
    const float* blin = (const float*)d_in[12];

    const int PADX = 200064;  // xhi: all N0 rows (gather sources span N0), 64-row mult
    const int PAD1 = 50048;   // 782*64 (gload_lds reads unmasked -> pad rows)
    const int PAD2 = 10112;   // 158*64

    char* ws = (char*)d_ws;
    size_t off = 0;
    auto alloc = [&](size_t bytes) {
        void* p = ws + off;
        off += (bytes + 255) & ~(size_t)255;
        return p;
    };
    // cnt0 and cnt1 adjacent -> one memset covers both (incl. alignment pad)
    int* cnt0  = (int*)alloc((size_t)N1 * 4);
    int* cnt1  = (int*)alloc((size_t)N2 * 4);
    size_t cnt_span = (size_t)((char*)cnt1 - (char*)cnt0) + (size_t)N2 * 4;
    int* eidx0 = (int*)alloc((size_t)N1 * CAP * 4);
    int* eidx1 = (int*)alloc((size_t)N2 * CAP * 4);
    unsigned short* agg0hi = (unsigned short*)alloc((size_t)PAD1 * D * 2);
    unsigned short* xhi    = (unsigned short*)alloc((size_t)PADX * D * 2);
    unsigned short* h0hi   = (unsigned short*)alloc((size_t)N1 * D * 2);
    unsigned short* agg1hi = (unsigned short*)alloc((size_t)PAD2 * D * 2);
    float* h1f = (float*)alloc((size_t)N2 * D * 4);
    unsigned short* WThi0 = (unsigned short*)alloc((size_t)D * 512 * 2);
    unsigned short* WTlo0 = (unsigned short*)alloc((size_t)D * 512 * 2);
    unsigned short* WThi1 = (unsigned short*)alloc((size_t)D * 512 * 2);
    unsigned short* WTlo1 = (unsigned short*)alloc((size_t)D * 512 * 2);

    hipMemsetAsync(cnt0, 0, cnt_span, stream);

    prep<<<CAST_B + PACK_B, 256, 0, stream>>>(
        x, xhi, src0, dst0, cnt0, eidx0, src1, dst1, cnt1, eidx1,
        Wl0, Wr0, WThi0, WTlo0, Wl1, Wr1, WThi1, WTlo1);

    aggregate_h<<<(N1 + 3) / 4, 256, 0, stream>>>(xhi, cnt0, eidx0, agg0hi, N1);
    gemm_split<0><<<dim3((N1 + BM - 1) / BM, 2), 256, 0, stream>>>(
        agg0hi, xhi, WThi0, WTlo0, bl0, h0hi, (float*)nullptr, N1);

    aggregate_h<<<(N2 + 3) / 4, 256, 0, stream>>>(h0hi, cnt1, eidx1, agg1hi, N2);
    gemm_split<1><<<dim3((N2 + BM - 1) / BM, 2), 256, 0, stream>>>(
        agg1hi, h0hi, WThi1, WTlo1, bl1, (unsigned short*)nullptr, h1f, N2);

    final_softmax<<<(N2 + FS_ROWS - 1) / FS_ROWS, 256, 0, stream>>>(
        h1f, Wlin, blin, (float*)d_out, N2);
}